// Round 17
// baseline (220.791 us; speedup 1.0000x reference)
//
#include <hip/hip_runtime.h>

#define QLEN 1024
#define BSZ  4
#define DM   512
#define NH   8
#define DH   64
#define FFD  2048

static constexpr float LN_EPS = 1e-5f;

typedef __attribute__((ext_vector_type(8))) short short8_t;  // 8 bf16 (4 VGPRs)
typedef __attribute__((ext_vector_type(4))) float f32x4;

__device__ __forceinline__ ushort f2b(float f) {
  uint u = __float_as_uint(f);
  return (ushort)((u + 0x7FFFu + ((u >> 16) & 1u)) >> 16);   // RNE
}
__device__ __forceinline__ float b2f(ushort h) {
  return __uint_as_float(((uint)h) << 16);
}

// ---------------------------------------------------------------------------
// Fused preprocessing: pe (2048 blk) | cvt src (1024) | cvt o_w (128) |
// cvt w1 (512) | cvt w2 (512) | trans512 (1024). Grid 5248 x 256.
// ---------------------------------------------------------------------------
__device__ __forceinline__ void cvt8_body(const float* in, ushort* out, int idx) {
  const float4 f0 = *reinterpret_cast<const float4*>(in + (size_t)idx * 8);
  const float4 f1 = *reinterpret_cast<const float4*>(in + (size_t)idx * 8 + 4);
  uint p0 = f2b(f0.x) | ((uint)f2b(f0.y) << 16);
  uint p1 = f2b(f0.z) | ((uint)f2b(f0.w) << 16);
  uint p2 = f2b(f1.x) | ((uint)f2b(f1.y) << 16);
  uint p3 = f2b(f1.z) | ((uint)f2b(f1.w) << 16);
  int4 st; st.x = (int)p0; st.y = (int)p1; st.z = (int)p2; st.w = (int)p3;
  *reinterpret_cast<int4*>(out + (size_t)idx * 8) = st;
}

__global__ __launch_bounds__(256) void prep_kernel(
    const float* __restrict__ src, const float* __restrict__ o_w,
    const float* __restrict__ w1, const float* __restrict__ w2,
    const float* __restrict__ qw, const float* __restrict__ kw,
    const float* __restrict__ vw, const float* __restrict__ rw,
    ushort* __restrict__ peb, ushort* __restrict__ srcb,
    ushort* __restrict__ owb, ushort* __restrict__ w1b,
    ushort* __restrict__ w2b, ushort* __restrict__ qkvw,
    ushort* __restrict__ rwT) {
  __shared__ float tile[32][33];
  const int bid = blockIdx.x, t = threadIdx.x;
  if (bid < 2048) {
    const int idx = bid * 256 + t;
    const int r = idx >> 9, f = idx & 511, f0 = f & 255;
    float invf = __expf(-(float)f0 * (9.210340371976184f / 256.0f));
    float arg  = (float)r * invf;
    peb[idx] = f2b((f < 256) ? __sinf(arg) : __cosf(arg));
  } else if (bid < 3072) {
    cvt8_body(src, srcb, (bid - 2048) * 256 + t);
  } else if (bid < 3200) {
    cvt8_body(o_w, owb, (bid - 3072) * 256 + t);
  } else if (bid < 3712) {
    cvt8_body(w1, w1b, (bid - 3200) * 256 + t);
  } else if (bid < 4224) {
    cvt8_body(w2, w2b, (bid - 3712) * 256 + t);
  } else {
    const int e = bid - 4224;
    const int z = e >> 8, rem = e & 255, bx = rem & 15, by = rem >> 4;
    const float* in = (z == 0) ? qw : (z == 1) ? kw : (z == 2) ? vw : rw;
    const int nd0 = bx * 32, h0 = by * 32;
    const int tx = t & 31, ty = t >> 5;
#pragma unroll
    for (int k = 0; k < 4; ++k)
      tile[ty + 8 * k][tx] = in[(size_t)(h0 + ty + 8 * k) * 512 + nd0 + tx];
    __syncthreads();
    ushort* out = (z < 3) ? (qkvw + (size_t)z * 512 * 512) : rwT;
#pragma unroll
    for (int k = 0; k < 4; ++k)
      out[(size_t)(nd0 + ty + 8 * k) * 512 + h0 + tx] = f2b(tile[tx][ty + 8 * k]);
  }
}

// ---------------------------------------------------------------------------
// 128x128 reg-staged GEMM body (bf16 out), shared by QKV and kprel.
// ---------------------------------------------------------------------------
__device__ __forceinline__ void gemm128_body(
    const ushort* A, const ushort* B, ushort* C,
    int N, int K, int bm, int bn, int t,
    ushort* As, ushort* Bs) {
  const int w = t >> 6, l = t & 63;
  const int lc = l & 15, lq = l >> 4;
  const int wr = (w >> 1) * 64, wc = (w & 1) * 64;
  const int sr = t >> 2, sk = (t & 3) * 8;

  f32x4 acc[4][4];
#pragma unroll
  for (int i = 0; i < 4; ++i)
#pragma unroll
    for (int j = 0; j < 4; ++j) acc[i][j] = (f32x4){0.f, 0.f, 0.f, 0.f};

  int4 a0v = *reinterpret_cast<const int4*>(A + (size_t)(bm + sr) * K + sk);
  int4 a1v = *reinterpret_cast<const int4*>(A + (size_t)(bm + 64 + sr) * K + sk);
  int4 b0v = *reinterpret_cast<const int4*>(B + (size_t)(bn + sr) * K + sk);
  int4 b1v = *reinterpret_cast<const int4*>(B + (size_t)(bn + 64 + sr) * K + sk);

  for (int k0 = 0; k0 < K; k0 += 32) {
    *reinterpret_cast<int4*>(As + sr * 40 + sk) = a0v;
    *reinterpret_cast<int4*>(As + (64 + sr) * 40 + sk) = a1v;
    *reinterpret_cast<int4*>(Bs + sr * 40 + sk) = b0v;
    *reinterpret_cast<int4*>(Bs + (64 + sr) * 40 + sk) = b1v;
    __syncthreads();
    if (k0 + 32 < K) {
      a0v = *reinterpret_cast<const int4*>(A + (size_t)(bm + sr) * K + k0 + 32 + sk);
      a1v = *reinterpret_cast<const int4*>(A + (size_t)(bm + 64 + sr) * K + k0 + 32 + sk);
      b0v = *reinterpret_cast<const int4*>(B + (size_t)(bn + sr) * K + k0 + 32 + sk);
      b1v = *reinterpret_cast<const int4*>(B + (size_t)(bn + 64 + sr) * K + k0 + 32 + sk);
    }
    short8_t af[4], bf[4];
#pragma unroll
    for (int mf = 0; mf < 4; ++mf)
      af[mf] = *reinterpret_cast<const short8_t*>(As + (wr + mf * 16 + lc) * 40 + lq * 8);
#pragma unroll
    for (int nf = 0; nf < 4; ++nf)
      bf[nf] = *reinterpret_cast<const short8_t*>(Bs + (wc + nf * 16 + lc) * 40 + lq * 8);
#pragma unroll
    for (int mf = 0; mf < 4; ++mf)
#pragma unroll
      for (int nf = 0; nf < 4; ++nf)
        acc[mf][nf] = __builtin_amdgcn_mfma_f32_16x16x32_bf16(af[mf], bf[nf], acc[mf][nf], 0, 0, 0);
    __syncthreads();
  }

#pragma unroll
  for (int mf = 0; mf < 4; ++mf)
#pragma unroll
    for (int nf = 0; nf < 4; ++nf) {
      const int col = bn + wc + nf * 16 + lc;
#pragma unroll
      for (int reg = 0; reg < 4; ++reg) {
        const int row = bm + wr + mf * 16 + lq * 4 + reg;
        C[(size_t)row * N + col] = f2b(acc[mf][nf][reg]);
      }
    }
}

// Dual launch: blocks [0,384) = QKV (4096x1536x512); [384,416) = kprel
// (1024x512x512). One dispatch fills the machine, removes a launch gap.
__global__ __launch_bounds__(256) void gemm128_dual(
    const ushort* __restrict__ srcb, const ushort* __restrict__ qkvw,
    const ushort* __restrict__ peb, const ushort* __restrict__ rwT,
    ushort* __restrict__ qkv, ushort* __restrict__ kprel) {
  __shared__ ushort As[128 * 40];
  __shared__ ushort Bs[128 * 40];
  const int bid = blockIdx.x, t = threadIdx.x;
  if (bid < 384) {
    const int bx = bid % 12, by = bid / 12;
    gemm128_body(srcb, qkvw, qkv, 1536, 512, by * 128, bx * 128, t, As, Bs);
  } else {
    const int e = bid - 384;
    const int bx = e & 3, by = e >> 2;
    gemm128_body(peb, rwT, kprel, 512, 512, by * 128, bx * 128, t, As, Bs);
  }
}

// ---------------------------------------------------------------------------
// Reg-staged bf16 GEMM, 128x128 tile with bias+gelu epilogue (FFN1).
// ---------------------------------------------------------------------------
__global__ __launch_bounds__(256) void gemm128_gelu(
    const ushort* __restrict__ A, const ushort* __restrict__ B,
    const float* __restrict__ bias, ushort* __restrict__ Cout,
    int M, int N, int K) {
  __shared__ ushort As[128 * 40];
  __shared__ ushort Bs[128 * 40];
  const int t = threadIdx.x;
  const int w = t >> 6, l = t & 63;
  const int lc = l & 15, lq = l >> 4;
  const int bm = blockIdx.y * 128, bn = blockIdx.x * 128;
  const int wr = (w >> 1) * 64, wc = (w & 1) * 64;
  const int sr = t >> 2, sk = (t & 3) * 8;

  f32x4 acc[4][4];
#pragma unroll
  for (int i = 0; i < 4; ++i)
#pragma unroll
    for (int j = 0; j < 4; ++j) acc[i][j] = (f32x4){0.f, 0.f, 0.f, 0.f};

  int4 a0v = *reinterpret_cast<const int4*>(A + (size_t)(bm + sr) * K + sk);
  int4 a1v = *reinterpret_cast<const int4*>(A + (size_t)(bm + 64 + sr) * K + sk);
  int4 b0v = *reinterpret_cast<const int4*>(B + (size_t)(bn + sr) * K + sk);
  int4 b1v = *reinterpret_cast<const int4*>(B + (size_t)(bn + 64 + sr) * K + sk);

  for (int k0 = 0; k0 < K; k0 += 32) {
    *reinterpret_cast<int4*>(As + sr * 40 + sk) = a0v;
    *reinterpret_cast<int4*>(As + (64 + sr) * 40 + sk) = a1v;
    *reinterpret_cast<int4*>(Bs + sr * 40 + sk) = b0v;
    *reinterpret_cast<int4*>(Bs + (64 + sr) * 40 + sk) = b1v;
    __syncthreads();
    if (k0 + 32 < K) {
      a0v = *reinterpret_cast<const int4*>(A + (size_t)(bm + sr) * K + k0 + 32 + sk);
      a1v = *reinterpret_cast<const int4*>(A + (size_t)(bm + 64 + sr) * K + k0 + 32 + sk);
      b0v = *reinterpret_cast<const int4*>(B + (size_t)(bn + sr) * K + k0 + 32 + sk);
      b1v = *reinterpret_cast<const int4*>(B + (size_t)(bn + 64 + sr) * K + k0 + 32 + sk);
    }
    short8_t af[4], bf[4];
#pragma unroll
    for (int mf = 0; mf < 4; ++mf)
      af[mf] = *reinterpret_cast<const short8_t*>(As + (wr + mf * 16 + lc) * 40 + lq * 8);
#pragma unroll
    for (int nf = 0; nf < 4; ++nf)
      bf[nf] = *reinterpret_cast<const short8_t*>(Bs + (wc + nf * 16 + lc) * 40 + lq * 8);
#pragma unroll
    for (int mf = 0; mf < 4; ++mf)
#pragma unroll
      for (int nf = 0; nf < 4; ++nf)
        acc[mf][nf] = __builtin_amdgcn_mfma_f32_16x16x32_bf16(af[mf], bf[nf], acc[mf][nf], 0, 0, 0);
    __syncthreads();
  }

#pragma unroll
  for (int mf = 0; mf < 4; ++mf)
#pragma unroll
    for (int nf = 0; nf < 4; ++nf) {
      const int col = bn + wc + nf * 16 + lc;
#pragma unroll
      for (int reg = 0; reg < 4; ++reg) {
        const int row = bm + wr + mf * 16 + lq * 4 + reg;
        float v = acc[mf][nf][reg] + bias[col];
        v = 0.5f * v * (1.0f + erff(v * 0.70710678118654752f));
        Cout[(size_t)row * N + col] = f2b(v);
      }
    }
}

// ---------------------------------------------------------------------------
// K-split reg-staged GEMM, 64x128 tile, f32 partial out (no bias).
// ---------------------------------------------------------------------------
__global__ __launch_bounds__(256) void gemm_split(
    const ushort* __restrict__ A, const ushort* __restrict__ B,
    float* __restrict__ Cout, int M, int N, int K, int halfK) {
  __shared__ ushort As[64 * 40];
  __shared__ ushort Bs[128 * 40];
  const int t = threadIdx.x;
  const int w = t >> 6, l = t & 63;
  const int lc = l & 15, lq = l >> 4;
  const int bm = blockIdx.y * 64, bn = blockIdx.x * 128;
  const int wr = (w >> 1) * 32, wc = (w & 1) * 64;
  const int sr = t >> 2, sk = (t & 3) * 8;
  const int kbeg = blockIdx.z * halfK, kend = kbeg + halfK;
  float* C = Cout + (size_t)blockIdx.z * M * N;

  f32x4 acc[2][4];
#pragma unroll
  for (int i = 0; i < 2; ++i)
#pragma unroll
    for (int j = 0; j < 4; ++j) acc[i][j] = (f32x4){0.f, 0.f, 0.f, 0.f};

  int4 a_v = *reinterpret_cast<const int4*>(A + (size_t)(bm + sr) * K + kbeg + sk);
  int4 b0v = *reinterpret_cast<const int4*>(B + (size_t)(bn + sr) * K + kbeg + sk);
  int4 b1v = *reinterpret_cast<const int4*>(B + (size_t)(bn + 64 + sr) * K + kbeg + sk);

  for (int k0 = kbeg; k0 < kend; k0 += 32) {
    *reinterpret_cast<int4*>(As + sr * 40 + sk) = a_v;
    *reinterpret_cast<int4*>(Bs + sr * 40 + sk) = b0v;
    *reinterpret_cast<int4*>(Bs + (64 + sr) * 40 + sk) = b1v;
    __syncthreads();
    if (k0 + 32 < kend) {
      a_v = *reinterpret_cast<const int4*>(A + (size_t)(bm + sr) * K + k0 + 32 + sk);
      b0v = *reinterpret_cast<const int4*>(B + (size_t)(bn + sr) * K + k0 + 32 + sk);
      b1v = *reinterpret_cast<const int4*>(B + (size_t)(bn + 64 + sr) * K + k0 + 32 + sk);
    }
    short8_t af[2], bf[4];
#pragma unroll
    for (int mf = 0; mf < 2; ++mf)
      af[mf] = *reinterpret_cast<const short8_t*>(As + (wr + mf * 16 + lc) * 40 + lq * 8);
#pragma unroll
    for (int nf = 0; nf < 4; ++nf)
      bf[nf] = *reinterpret_cast<const short8_t*>(Bs + (wc + nf * 16 + lc) * 40 + lq * 8);
#pragma unroll
    for (int mf = 0; mf < 2; ++mf)
#pragma unroll
      for (int nf = 0; nf < 4; ++nf)
        acc[mf][nf] = __builtin_amdgcn_mfma_f32_16x16x32_bf16(af[mf], bf[nf], acc[mf][nf], 0, 0, 0);
    __syncthreads();
  }

#pragma unroll
  for (int mf = 0; mf < 2; ++mf)
#pragma unroll
    for (int nf = 0; nf < 4; ++nf) {
      const int col = bn + wc + nf * 16 + lc;
#pragma unroll
      for (int reg = 0; reg < 4; ++reg) {
        const int row = bm + wr + mf * 16 + lq * 4 + reg;
        C[(size_t)row * N + col] = acc[mf][nf][reg];
      }
    }
}

// ---------------------------------------------------------------------------
// Merged repack (blocks [0,3072)) + kprelF (blocks [3072,3600), 128 active).
// ---------------------------------------------------------------------------
__global__ __launch_bounds__(256) void repack_kernel(
    const ushort* __restrict__ qkv, const float* __restrict__ rwb,
    const float* __restrict__ rrb, const ushort* __restrict__ kprel,
    ushort* __restrict__ qaF, ushort* __restrict__ qbF,
    ushort* __restrict__ kF, ushort* __restrict__ vF,
    ushort* __restrict__ kprelF) {
  __shared__ ushort st[32][72];
  const int bid = blockIdx.x, t = threadIdx.x;
  const int l = t & 63, lc = l & 15, lq = l >> 4;

  if (bid >= 3072) {   // kprelF part (128 active threads)
    if (t < 128) {
      const int e = bid - 3072;          // e = m + 66*n
      const int m = e % 66, n = e / 66;
      const int kc = t >> 6;
      const int rho = m * 16 - 31 + lc;
      short8_t v;
      if (rho >= 0 && rho < 1024)
        v = *reinterpret_cast<const short8_t*>(kprel + (size_t)rho * 512 + n * 64 + kc * 32 + lq * 8);
      else
#pragma unroll
        for (int e2 = 0; e2 < 8; ++e2) v[e2] = 0;
      const size_t o = ((size_t)((n * 66 + m) * 2 + kc)) * 512 + l * 8;
      *reinterpret_cast<short8_t*>(kprelF + o) = v;
    }
    return;
  }

  const int tile = bid & 31, head = (bid >> 5) & 31, role = bid >> 10;
  const int b = head >> 3, n = head & 7;
  const int s0 = tile * 32;
  const int sec = (role == 0) ? 0 : (role == 1) ? 512 : 1024;
  {
    const int s = t >> 3, d8 = (t & 7) * 8;
    int4 rd = *reinterpret_cast<const int4*>(
        qkv + (size_t)((s0 + s) * 4 + b) * 1536 + sec + n * 64 + d8);
    *reinterpret_cast<int4*>(&st[s][d8]) = rd;
  }
  __syncthreads();
  if (role == 0) {
    const int f = t >> 6, sub = f >> 1, kc = f & 1;
    const int row = sub * 16 + lc, k = kc * 32 + lq * 8;
    short8_t qv = *reinterpret_cast<const short8_t*>(&st[row][k]);
    const float4 w0 = *reinterpret_cast<const float4*>(rwb + n * 64 + k);
    const float4 w1 = *reinterpret_cast<const float4*>(rwb + n * 64 + k + 4);
    const float4 u0 = *reinterpret_cast<const float4*>(rrb + n * 64 + k);
    const float4 u1 = *reinterpret_cast<const float4*>(rrb + n * 64 + k + 4);
    const float wv[8] = {w0.x, w0.y, w0.z, w0.w, w1.x, w1.y, w1.z, w1.w};
    const float uv[8] = {u0.x, u0.y, u0.z, u0.w, u1.x, u1.y, u1.z, u1.w};
    short8_t a_, b_;
#pragma unroll
    for (int e = 0; e < 8; ++e) {
      float q = b2f((ushort)qv[e]);
      a_[e] = (short)f2b(q + wv[e]);
      b_[e] = (short)f2b(q + uv[e]);
    }
    const size_t o = ((size_t)((head * 64 + tile * 2 + sub) * 2 + kc)) * 512 + l * 8;
    *reinterpret_cast<short8_t*>(qaF + o) = a_;
    *reinterpret_cast<short8_t*>(qbF + o) = b_;
  } else if (role == 1) {
    const int f = t >> 6, sub = f >> 1, kc = f & 1;
    const int row = sub * 16 + lc, k = kc * 32 + lq * 8;
    short8_t kv = *reinterpret_cast<const short8_t*>(&st[row][k]);
    const size_t o = ((size_t)((head * 64 + tile * 2 + sub) * 2 + kc)) * 512 + l * 8;
    *reinterpret_cast<short8_t*>(kF + o) = kv;
  } else {
    const int nf = t >> 6;
    short8_t vv;
#pragma unroll
    for (int e = 0; e < 8; ++e) vv[e] = (short)st[lq * 8 + e][nf * 16 + lc];
    const size_t o = ((size_t)((head * 32 + tile) * 4 + nf)) * 512 + l * 8;
    *reinterpret_cast<short8_t*>(vF + o) = vv;
  }
}

// ---------------------------------------------------------------------------
// MFMA flash attention: 16-row i-tiles x 32-col j-tiles, triangle-paired,
// fragment-linear inputs, XCD-aware head grouping, defer-max + deferred-l
// softmax, ds_bpermute G gather, and SOFTWARE PREFETCH: next iteration's
// K/kpF frags load during current softmax; V issued at iteration start.
// Merge phase uses per-wave obuf regions (no serialized accumulation).
// LDS: 4x(16x68 f32) obuf + mlb = 17920 B (P aliased in first 5120).
// ---------------------------------------------------------------------------
__global__ __launch_bounds__(256, 4) void attn_mfma(
    const ushort* __restrict__ qaF, const ushort* __restrict__ qbF,
    const ushort* __restrict__ kF, const ushort* __restrict__ kpF,
    const ushort* __restrict__ vF, ushort* __restrict__ av) {
  __shared__ __align__(16) char smemU[17920];

  const int t = threadIdx.x, w = t >> 6, l = t & 63;
  const int lid = blockIdx.y * 32 + blockIdx.x;
  const int head = (lid & 7) * 4 + ((lid >> 3) & 3);     // lid%8 -> XCD slot
  const int pr   = lid >> 5;
  const int b = head >> 3, n = head & 7;
  const int lc = l & 15, lq = l >> 4;

  ushort* pw = reinterpret_cast<ushort*>(smemU) + w * (16 * 40);

#define LOADK(dst, jt_)                                                        \
  {                                                                            \
    const int jb16 = ((jt_) * 32) >> 4;                                        \
    _Pragma("unroll")                                                          \
    for (int kc = 0; kc < 2; ++kc)                                             \
      _Pragma("unroll")                                                        \
      for (int nf = 0; nf < 2; ++nf)                                           \
        dst[kc][nf] = *reinterpret_cast<const short8_t*>(                      \
            kF + ((size_t)((head * 64 + jb16 + nf) * 2 + kc)) * 512 + l * 8);  \
  }
#define LOADP(dst, jt_)                                                        \
  {                                                                            \
    const int Dm = (i0 - (jt_) * 32) >> 4;                                     \
    _Pragma("unroll")                                                          \
    for (int kc = 0; kc < 2; ++kc)                                             \
      _Pragma("unroll")                                                        \
      for (int nf = 0; nf < 3; ++nf)                                           \
        dst[kc][nf] = *reinterpret_cast<const short8_t*>(                      \
            kpF + ((size_t)((n * 66 + Dm + nf) * 2 + kc)) * 512 + l * 8);      \
  }

  for (int ph = 0; ph < 2; ++ph) {
    const int it = ph ? 63 - pr : pr;
    const int i0 = it * 16;
    __syncthreads();   // protect LDS from previous phase

    short8_t qa[2], qb[2];
    {
      const size_t qo = ((size_t)(head * 64 + it) * 2) * 512 + l * 8;
      qa[0] = *reinterpret_cast<const short8_t*>(qaF + qo);
      qa[1] = *reinterpret_cast<const short8_t*>(qaF + qo + 512);
      qb[0] = *reinterpret_cast<const short8_t*>(qbF + qo);
      qb[1] = *reinterpret_cast<const short8_t*>(qbF + qo + 512);
    }

    float m_run[4], l_lane[4];
    f32x4 oacc[4];
#pragma unroll
    for (int reg = 0; reg < 4; ++reg) { m_run[reg] = -1e30f; l_lane[reg] = 0.f; }
#pragma unroll
    for (int nf = 0; nf < 4; ++nf) oacc[nf] = (f32x4){0.f, 0.f, 0.f, 0.f};

    const int nj = it / 2 + 1;

    short8_t kfA[2][2], pfA[2][3];
    if (w < nj) { LOADK(kfA, w); LOADP(pfA, w); }

    for (int jt = w; jt < nj; jt += 4) {
      const int j0 = jt * 32;
      const int D = i0 - j0;
      const int jn = jt + 4;

      // V for CURRENT iteration, issued first (used last)
      short8_t vfv[4];
#pragma unroll
      for (int nf = 0; nf < 4; ++nf)
        vfv[nf] = *reinterpret_cast<const short8_t*>(
            vF + ((size_t)((head * 32 + jt) * 4 + nf)) * 512 + l * 8);

      f32x4 sacc[2];
#pragma unroll
      for (int nf = 0; nf < 2; ++nf) sacc[nf] = (f32x4){0.f, 0.f, 0.f, 0.f};
#pragma unroll
      for (int kc = 0; kc < 2; ++kc)
#pragma unroll
        for (int nf = 0; nf < 2; ++nf)
          sacc[nf] = __builtin_amdgcn_mfma_f32_16x16x32_bf16(qa[kc], kfA[kc][nf], sacc[nf], 0, 0, 0);

      f32x4 gacc[3];
#pragma unroll
      for (int nf = 0; nf < 3; ++nf) gacc[nf] = (f32x4){0.f, 0.f, 0.f, 0.f};
#pragma unroll
      for (int kc = 0; kc < 2; ++kc)
#pragma unroll
        for (int nf = 0; nf < 3; ++nf)
          gacc[nf] = __builtin_amdgcn_mfma_f32_16x16x32_bf16(qb[kc], pfA[kc][nf], gacc[nf], 0, 0, 0);

      // prefetch NEXT iteration's K/kpF during softmax
      short8_t kfB[2][2], pfB[2][3];
      if (jn < nj) { LOADK(kfB, jn); LOADP(pfB, jn); }

      // ---- G diagonal gather via ds_bpermute
      float s0v[4], s1v[4];
#pragma unroll
      for (int j = 0; j < 4; ++j) {
        const int r = lq * 4 + j;
        const int sl4 = ((((r + 15 - lc) & 15) | (lq << 4)) << 2);
        const float g0 = __int_as_float(__builtin_amdgcn_ds_bpermute(sl4, __float_as_int(gacc[0][j])));
        const float g1 = __int_as_float(__builtin_amdgcn_ds_bpermute(sl4, __float_as_int(gacc[1][j])));
        const float g2 = __int_as_float(__builtin_amdgcn_ds_bpermute(sl4, __float_as_int(gacc[2][j])));
        const bool sel = (r <= lc);
        const float Gu0 = sel ? g1 : g2;
        const float Gu1 = sel ? g0 : g1;
        float s0 = (sacc[0][j] + Gu0) * 0.125f;
        float s1 = (sacc[1][j] + Gu1) * 0.125f;
        if (D < 32) {
          if (lc > D + r) s0 = -1e30f;
          if (16 + lc > D + r) s1 = -1e30f;
        }
        s0v[j] = s0; s1v[j] = s1;
      }

      // ---- defer-max: common path has ZERO cross-lane ops
      bool ok = true;
#pragma unroll
      for (int reg = 0; reg < 4; ++reg)
        ok &= (fmaxf(s0v[reg], s1v[reg]) <= m_run[reg] + 8.0f);
      if (__all(ok ? 1 : 0)) {
#pragma unroll
        for (int reg = 0; reg < 4; ++reg) {
          const int r = lq * 4 + reg;
          const float p0 = __expf(s0v[reg] - m_run[reg]);
          const float p1 = __expf(s1v[reg] - m_run[reg]);
          l_lane[reg] += p0 + p1;
          pw[r * 40 + lc] = f2b(p0);
          pw[r * 40 + 16 + lc] = f2b(p1);
        }
      } else {
#pragma unroll
        for (int reg = 0; reg < 4; ++reg) {
          const int r = lq * 4 + reg;
          float tm = fmaxf(s0v[reg], s1v[reg]);
          tm = fmaxf(tm, __shfl_xor(tm, 1));
          tm = fmaxf(tm, __shfl_xor(tm, 2));
          tm = fmaxf(tm, __shfl_xor(tm, 4));
          tm = fmaxf(tm, __shfl_xor(tm, 8));
          const float mn = fmaxf(m_run[reg], tm);
          const float corr = __expf(m_run[reg] - mn);
          const float p0 = __expf(s0v[reg] - mn), p1 = __expf(s1v[reg] - mn);
          l_lane[reg] = l_lane[reg] * corr + (p0 + p1);
          m_run[reg] = mn;
#pragma unroll
          for (int nf = 0; nf < 4; ++nf) oacc[nf][reg] *= corr;
          pw[r * 40 + lc] = f2b(p0);
          pw[r * 40 + 16 + lc] = f2b(p1);
        }
      }

      short8_t pa = *reinterpret_cast<const short8_t*>(pw + lc * 40 + lq * 8);
#pragma unroll
      for (int nf = 0; nf < 4; ++nf)
        oacc[nf] = __builtin_amdgcn_mfma_f32_16x16x32_bf16(pa, vfv[nf], oacc[nf], 0, 0, 0);

      // rotate prefetched frags
#pragma unroll
      for (int kc = 0; kc < 2; ++kc) {
#pragma unroll
        for (int nf = 0; nf < 2; ++nf) kfA[kc][nf] = kfB[kc][nf];
#pragma unroll
        for (int nf = 0; nf < 3; ++nf) pfA[kc][nf] = pfB[kc][nf];
      }
    }

    // ---- one 16-lane l-reduction per phase (deferred from the loop)
    float l_run[4];
#pragma unroll
    for (int reg = 0; reg < 4; ++reg) {
      float v = l_lane[reg];
      v += __shfl_xor(v, 1);
      v += __shfl_xor(v, 2);
      v += __shfl_xor(v, 4);
      v += __shfl_xor(v, 8);
      l_run[reg] = v;
    }

    __syncthreads();
    float* obuf = reinterpret_cast<float*>(smemU);               // 4 x 16*68 f32
    float* mlb  = reinterpret_cast<float*>(smemU + 17408);       // 4*16*2 f32
    float* ow   = obuf + w * (16 * 68);

    if (lc == 0) {
#pragma unroll
      for (int reg = 0; reg < 4; ++reg) {
        const int r = lq * 4 + reg;
        mlb[(w * 16 + r) * 2 + 0] = m_run[reg];
        mlb[(w * 16 + r) * 2 + 1] = l_run[reg];
      }
    }
    __syncthreads();

    // per-wave scaled write (empty waves write 0: scl*oacc = 0*0)
    float scl[4];
#pragma unroll
    for (int reg = 0; reg < 4; ++reg) {
      const int r = lq * 4 + reg;
      const float m0 = mlb[r * 2], m1 = mlb[(16 + r) * 2],
                  m2 = mlb[(32 + r) * 2], m3 = mlb[(48 + r) * 2];
      const float ms = fmaxf(fmaxf(m0, m1), fmaxf(m2, m3));
      scl[reg] = __expf(mlb[(w * 16 + r) * 2] - ms);
    }
#pragma unroll
    for (int nf = 0; nf < 4; ++nf)
#pragma unroll
      for (int reg = 0; reg < 4; ++reg) {
        const int r = lq * 4 + reg;
        ow[r * 68 + nf * 16 + lc] = scl[reg] * oacc[nf][reg];
      }
    __syncthreads();

    {
      const int r = t >> 4, d0 = (t & 15) * 4;
      const float m0 = mlb[r * 2], m1 = mlb[(16 + r) * 2],
                  m2 = mlb[(32 + r) * 2], m3 = mlb[(48 + r) * 2];
      const float ms = fmaxf(fmaxf(m0, m1), fmaxf(m2, m3));
      const float ls = mlb[r * 2 + 1] * __expf(m0 - ms) + mlb[(16 + r) * 2 + 1] * __expf(m1 - ms) +
                       mlb[(32 + r) * 2 + 1] * __expf(m2 - ms) + mlb[(48 + r) * 2 + 1] * __expf(m3 - ms);
      const float inv = 1.f / ls;
      float o4[4];
#pragma unroll
      for (int e = 0; e < 4; ++e) {
        const int c = d0 + e;
        o4[e] = (obuf[r * 68 + c] + obuf[16 * 68 + r * 68 + c] +
                 obuf[2 * 16 * 68 + r * 68 + c] + obuf[3 * 16 * 68 + r * 68 + c]) * inv;
      }
      uint pk0 = (uint)f2b(o4[0]) | ((uint)f2b(o4[1]) << 16);
      uint pk1 = (uint)f2b(o4[2]) | ((uint)f2b(o4[3]) << 16);
      int2 st2; st2.x = (int)pk0; st2.y = (int)pk1;
      const int tok = (i0 + r) * 4 + b;
      *reinterpret_cast<int2*>(av + (size_t)tok * 512 + n * 64 + d0) = st2;
    }
  }
#undef LOADK
#undef LOADP
}

// ---------------------------------------------------------------------------
// LayerNorm kernels (f32 math). ln_res sums two o-proj K-split partials +
// residual; ln_final sums two FFN2 partials + b2 + residual, then final LN.
// ---------------------------------------------------------------------------
__device__ __forceinline__ float blk_sum(float v, volatile float* sb) {
  v += __shfl_xor(v, 1);  v += __shfl_xor(v, 2);  v += __shfl_xor(v, 4);
  v += __shfl_xor(v, 8);  v += __shfl_xor(v, 16); v += __shfl_xor(v, 32);
  const int t = threadIdx.x;
  if ((t & 63) == 0) sb[t >> 6] = v;
  __syncthreads();
  v = sb[0] + sb[1] + sb[2] + sb[3];
  __syncthreads();
  return v;
}

__global__ __launch_bounds__(256) void ln_res_kernel(
    const float* __restrict__ aoa, const float* __restrict__ aob,
    const float* __restrict__ res,
    const float* __restrict__ g, const float* __restrict__ be,
    float* __restrict__ out, ushort* __restrict__ outb) {
  __shared__ float sb[4];
  const int row = blockIdx.x, t = threadIdx.x;
  const size_t base = (size_t)row * DM;
  const float x0 = aoa[base + t] + aob[base + t] + res[base + t];
  const float x1 = aoa[base + t + 256] + aob[base + t + 256] + res[base + t + 256];
  const float mu = blk_sum(x0 + x1, sb) * (1.f / DM);
  const float d0 = x0 - mu, d1 = x1 - mu;
  const float var = blk_sum(d0 * d0 + d1 * d1, sb) * (1.f / DM);
  const float inv = rsqrtf(var + LN_EPS);
  const float z0 = d0 * inv * g[t] + be[t];
  const float z1 = d1 * inv * g[t + 256] + be[t + 256];
  out[base + t] = z0;
  out[base + t + 256] = z1;
  outb[base + t] = f2b(z0);
  outb[base + t + 256] = f2b(z1);
}

__global__ __launch_bounds__(256) void ln_final_kernel(
    const float* __restrict__ ya, const float* __restrict__ yb,
    const float* __restrict__ b2, const float* __restrict__ xres,
    const float* __restrict__ g2, const float* __restrict__ be2,
    const float* __restrict__ gf, const float* __restrict__ bf,
    float* __restrict__ out) {
  __shared__ float sb[4];
  const int row = blockIdx.x, t = threadIdx.x;
  const size_t base = (size_t)row * DM;
  const float x0 = ya[base + t] + yb[base + t] + b2[t] + xres[base + t];
  const float x1 = ya[base + t + 256] + yb[base + t + 256] + b2[t + 256] + xres[base + t + 256];
  const float mu = blk_sum(x0 + x1, sb) * (1.f / DM);
  const float d0 = x0 - mu, d1 = x1 - mu;
  const float var = blk_sum(d0 * d0 + d1 * d1, sb) * (1.f / DM);
  const float inv = rsqrtf(var + LN_EPS);
  const float z0 = d0 * inv * g2[t] + be2[t];
  const float z1 = d1 * inv * g2[t + 256] + be2[t + 256];
  const float mu2 = blk_sum(z0 + z1, sb) * (1.f / DM);
  const float e0 = z0 - mu2, e1 = z1 - mu2;
  const float var2 = blk_sum(e0 * e0 + e1 * e1, sb) * (1.f / DM);
  const float inv2 = rsqrtf(var2 + LN_EPS);
  out[base + t]       = e0 * inv2 * gf[t] + bf[t];
  out[base + t + 256] = e1 * inv2 * gf[t + 256] + bf[t + 256];
}

// ---------------------------------------------------------------------------
extern "C" void kernel_launch(void* const* d_in, const int* in_sizes, int n_in,
                              void* d_out, int out_size, void* d_ws, size_t ws_size,
                              hipStream_t stream) {
  const float* src = (const float*)d_in[0];
  const float* q_w = (const float*)d_in[1];
  const float* k_w = (const float*)d_in[2];
  const float* v_w = (const float*)d_in[3];
  const float* r_w = (const float*)d_in[4];
  const float* o_w = (const float*)d_in[5];
  const float* rwb = (const float*)d_in[6];
  const float* rrb = (const float*)d_in[7];
  const float* w1  = (const float*)d_in[8];
  const float* b1  = (const float*)d_in[9];
  const float* w2  = (const float*)d_in[10];
  const float* b2  = (const float*)d_in[11];
  const float* g1  = (const float*)d_in[12];
  const float* be1 = (const float*)d_in[13];
  const float* g2  = (const float*)d_in[14];
  const float* be2 = (const float*)d_in[15];
  const float* gf  = (const float*)d_in[16];
  const float* bf  = (const float*)d_in[17];

  char* ws = (char*)d_ws;
  const size_t KB = 1024, MB = 1024 * 1024;
  ushort* srcb   = (ushort*)(ws);                        // 0    - 4 MB
  ushort* qkvw   = (ushort*)(ws + 4 * MB);               // 4    - 5.5
  ushort* rwT    = (ushort*)(ws + 5 * MB + 512 * KB);    // 5.5  - 6
  ushort* owb    = (ushort*)(ws + 6 * MB);               // 6    - 6.5
  ushort* w1b    = (ushort*)(ws + 6 * MB + 512 * KB);    // 6.5  - 8.5
  ushort* w2b    = (ushort*)(ws + 8 * MB + 512 * KB);    // 8.5  - 10.5
  ushort* peb    = (ushort*)(ws + 10 * MB + 512 * KB);   // 10.5 - 11.5
  ushort* qkv    = (ushort*)(ws + 11 * MB + 512 * KB);   // 11.5 - 23.5
  ushort* kprel  = (ushort*)(ws + 23 * MB + 512 * KB);   // 23.5 - 24.5
  ushort* qaF    = (ushort*)(ws + 24 * MB + 512 * KB);   // 24.5 - 28.5
  ushort* qbF    = (ushort*)(ws + 28 * MB + 512 * KB);   // 28.5 - 32.5
  ushort* kF     = (ushort*)(ws + 32 * MB + 512 * KB);   // 32.5 - 36.5
  ushort* vF     = (ushort*)(ws + 36 * MB + 512 * KB);   // 36.5 - 40.5
  ushort* kprelF = (ushort*)(ws + 40 * MB + 512 * KB);   // 40.5 - 41.6 (66 slots)
  ushort* av     = (ushort*)(ws + 42 * MB);              // 42   - 46
  float*  aoP    = (float*) (ws + 24 * MB + 512 * KB);   // 24.5 - 40.5 (2x8MB, over qaF..vF, dead after attn)
  float*  x1     = (float*) (ws + 46 * MB);              // 46   - 54
  ushort* x1b    = (ushort*)(ws + 42 * MB);              // 42   - 46 (over av, dead after o-proj)
  ushort* h      = (ushort*)(ws + 11 * MB + 512 * KB);   // 11.5 - 27.5 (qkv/kprel/aoP-head dead)
  float*  y2P    = (float*) (ws + 27 * MB + 512 * KB);   // 27.5 - 43.5 (2x8MB, aoP-tail/kprelF/x1b dead)
  float*  outp   = (float*)d_out;

  // fused preprocessing (pe + 4 cvt + weight transpose)
  prep_kernel<<<dim3(5248), 256, 0, stream>>>(src, o_w, w1, w2, q_w, k_w, v_w, r_w,
                                              peb, srcb, owb, w1b, w2b, qkvw, rwT);

  // fused QKV + kprel projections (one dispatch)
  gemm128_dual<<<dim3(416), 256, 0, stream>>>(srcb, qkvw, peb, rwT, qkv, kprel);

  // fused fragment-linear repack + kprelF
  repack_kernel<<<dim3(3600), 256, 0, stream>>>(qkv, rwb, rrb, kprel, qaF, qbF, kF, vF, kprelF);

  attn_mfma<<<dim3(32, 32), 256, 0, stream>>>(qaF, qbF, kF, kprelF, vF, av);

  // o-proj K-split x2 -> f32 partials; summed in ln_res
  gemm_split<<<dim3(4, 64, 2), 256, 0, stream>>>(av, owb, aoP, 4096, 512, 512, 256);
  ln_res_kernel<<<dim3(4096), 256, 0, stream>>>(aoP, aoP + 2097152, src, g1, be1, x1, x1b);

  gemm128_gelu<<<dim3(16, 32), 256, 0, stream>>>(x1b, w1b, b1, h, 4096, 2048, 512);
  // FFN2 K-split x2 -> f32 partials; summed (+b2) in ln_final
  gemm_split<<<dim3(4, 64, 2), 256, 0, stream>>>(h, w2b, y2P, 4096, 512, 2048, 1024);

  ln_final_kernel<<<dim3(4096), 256, 0, stream>>>(y2P, y2P + 2097152, b2, x1, g2, be2, gf, bf, outp);
}

// Round 18
// 134.125 us; speedup vs baseline: 1.6462x; 1.6462x over previous
//
#include <hip/hip_runtime.h>

#define QLEN 1024
#define BSZ  4
#define DM   512
#define NH   8
#define DH   64
#define FFD  2048

static constexpr float LN_EPS = 1e-5f;

typedef __attribute__((ext_vector_type(8))) short short8_t;  // 8 bf16 (4 VGPRs)
typedef __attribute__((ext_vector_type(4))) float f32x4;

__device__ __forceinline__ ushort f2b(float f) {
  uint u = __float_as_uint(f);
  return (ushort)((u + 0x7FFFu + ((u >> 16) & 1u)) >> 16);   // RNE
}
__device__ __forceinline__ float b2f(ushort h) {
  return __uint_as_float(((uint)h) << 16);
}

// ---------------------------------------------------------------------------
// Fused preprocessing: pe (2048 blk) | cvt src (1024) | cvt o_w (128) |
// cvt w1 (512) | cvt w2 (512) | trans512 (1024). Grid 5248 x 256.
// ---------------------------------------------------------------------------
__device__ __forceinline__ void cvt8_body(const float* in, ushort* out, int idx) {
  const float4 f0 = *reinterpret_cast<const float4*>(in + (size_t)idx * 8);
  const float4 f1 = *reinterpret_cast<const float4*>(in + (size_t)idx * 8 + 4);
  uint p0 = f2b(f0.x) | ((uint)f2b(f0.y) << 16);
  uint p1 = f2b(f0.z) | ((uint)f2b(f0.w) << 16);
  uint p2 = f2b(f1.x) | ((uint)f2b(f1.y) << 16);
  uint p3 = f2b(f1.z) | ((uint)f2b(f1.w) << 16);
  int4 st; st.x = (int)p0; st.y = (int)p1; st.z = (int)p2; st.w = (int)p3;
  *reinterpret_cast<int4*>(out + (size_t)idx * 8) = st;
}

__global__ __launch_bounds__(256) void prep_kernel(
    const float* __restrict__ src, const float* __restrict__ o_w,
    const float* __restrict__ w1, const float* __restrict__ w2,
    const float* __restrict__ qw, const float* __restrict__ kw,
    const float* __restrict__ vw, const float* __restrict__ rw,
    ushort* __restrict__ peb, ushort* __restrict__ srcb,
    ushort* __restrict__ owb, ushort* __restrict__ w1b,
    ushort* __restrict__ w2b, ushort* __restrict__ qkvw,
    ushort* __restrict__ rwT) {
  __shared__ float tile[32][33];
  const int bid = blockIdx.x, t = threadIdx.x;
  if (bid < 2048) {
    const int idx = bid * 256 + t;
    const int r = idx >> 9, f = idx & 511, f0 = f & 255;
    float invf = __expf(-(float)f0 * (9.210340371976184f / 256.0f));
    float arg  = (float)r * invf;
    peb[idx] = f2b((f < 256) ? __sinf(arg) : __cosf(arg));
  } else if (bid < 3072) {
    cvt8_body(src, srcb, (bid - 2048) * 256 + t);
  } else if (bid < 3200) {
    cvt8_body(o_w, owb, (bid - 3072) * 256 + t);
  } else if (bid < 3712) {
    cvt8_body(w1, w1b, (bid - 3200) * 256 + t);
  } else if (bid < 4224) {
    cvt8_body(w2, w2b, (bid - 3712) * 256 + t);
  } else {
    const int e = bid - 4224;
    const int z = e >> 8, rem = e & 255, bx = rem & 15, by = rem >> 4;
    const float* in = (z == 0) ? qw : (z == 1) ? kw : (z == 2) ? vw : rw;
    const int nd0 = bx * 32, h0 = by * 32;
    const int tx = t & 31, ty = t >> 5;
#pragma unroll
    for (int k = 0; k < 4; ++k)
      tile[ty + 8 * k][tx] = in[(size_t)(h0 + ty + 8 * k) * 512 + nd0 + tx];
    __syncthreads();
    ushort* out = (z < 3) ? (qkvw + (size_t)z * 512 * 512) : rwT;
#pragma unroll
    for (int k = 0; k < 4; ++k)
      out[(size_t)(nd0 + ty + 8 * k) * 512 + h0 + tx] = f2b(tile[tx][ty + 8 * k]);
  }
}

// ---------------------------------------------------------------------------
// 128x128 reg-staged GEMM body (bf16 out), shared by QKV and kprel.
// ---------------------------------------------------------------------------
__device__ __forceinline__ void gemm128_body(
    const ushort* A, const ushort* B, ushort* C,
    int N, int K, int bm, int bn, int t,
    ushort* As, ushort* Bs) {
  const int w = t >> 6, l = t & 63;
  const int lc = l & 15, lq = l >> 4;
  const int wr = (w >> 1) * 64, wc = (w & 1) * 64;
  const int sr = t >> 2, sk = (t & 3) * 8;

  f32x4 acc[4][4];
#pragma unroll
  for (int i = 0; i < 4; ++i)
#pragma unroll
    for (int j = 0; j < 4; ++j) acc[i][j] = (f32x4){0.f, 0.f, 0.f, 0.f};

  int4 a0v = *reinterpret_cast<const int4*>(A + (size_t)(bm + sr) * K + sk);
  int4 a1v = *reinterpret_cast<const int4*>(A + (size_t)(bm + 64 + sr) * K + sk);
  int4 b0v = *reinterpret_cast<const int4*>(B + (size_t)(bn + sr) * K + sk);
  int4 b1v = *reinterpret_cast<const int4*>(B + (size_t)(bn + 64 + sr) * K + sk);

  for (int k0 = 0; k0 < K; k0 += 32) {
    *reinterpret_cast<int4*>(As + sr * 40 + sk) = a0v;
    *reinterpret_cast<int4*>(As + (64 + sr) * 40 + sk) = a1v;
    *reinterpret_cast<int4*>(Bs + sr * 40 + sk) = b0v;
    *reinterpret_cast<int4*>(Bs + (64 + sr) * 40 + sk) = b1v;
    __syncthreads();
    if (k0 + 32 < K) {
      a0v = *reinterpret_cast<const int4*>(A + (size_t)(bm + sr) * K + k0 + 32 + sk);
      a1v = *reinterpret_cast<const int4*>(A + (size_t)(bm + 64 + sr) * K + k0 + 32 + sk);
      b0v = *reinterpret_cast<const int4*>(B + (size_t)(bn + sr) * K + k0 + 32 + sk);
      b1v = *reinterpret_cast<const int4*>(B + (size_t)(bn + 64 + sr) * K + k0 + 32 + sk);
    }
    short8_t af[4], bf[4];
#pragma unroll
    for (int mf = 0; mf < 4; ++mf)
      af[mf] = *reinterpret_cast<const short8_t*>(As + (wr + mf * 16 + lc) * 40 + lq * 8);
#pragma unroll
    for (int nf = 0; nf < 4; ++nf)
      bf[nf] = *reinterpret_cast<const short8_t*>(Bs + (wc + nf * 16 + lc) * 40 + lq * 8);
#pragma unroll
    for (int mf = 0; mf < 4; ++mf)
#pragma unroll
      for (int nf = 0; nf < 4; ++nf)
        acc[mf][nf] = __builtin_amdgcn_mfma_f32_16x16x32_bf16(af[mf], bf[nf], acc[mf][nf], 0, 0, 0);
    __syncthreads();
  }

#pragma unroll
  for (int mf = 0; mf < 4; ++mf)
#pragma unroll
    for (int nf = 0; nf < 4; ++nf) {
      const int col = bn + wc + nf * 16 + lc;
#pragma unroll
      for (int reg = 0; reg < 4; ++reg) {
        const int row = bm + wr + mf * 16 + lq * 4 + reg;
        C[(size_t)row * N + col] = f2b(acc[mf][nf][reg]);
      }
    }
}

// Dual launch: blocks [0,384) = QKV (4096x1536x512); [384,416) = kprel
// (1024x512x512). One dispatch fills the machine, removes a launch gap.
__global__ __launch_bounds__(256) void gemm128_dual(
    const ushort* __restrict__ srcb, const ushort* __restrict__ qkvw,
    const ushort* __restrict__ peb, const ushort* __restrict__ rwT,
    ushort* __restrict__ qkv, ushort* __restrict__ kprel) {
  __shared__ ushort As[128 * 40];
  __shared__ ushort Bs[128 * 40];
  const int bid = blockIdx.x, t = threadIdx.x;
  if (bid < 384) {
    const int bx = bid % 12, by = bid / 12;
    gemm128_body(srcb, qkvw, qkv, 1536, 512, by * 128, bx * 128, t, As, Bs);
  } else {
    const int e = bid - 384;
    const int bx = e & 3, by = e >> 2;
    gemm128_body(peb, rwT, kprel, 512, 512, by * 128, bx * 128, t, As, Bs);
  }
}

// ---------------------------------------------------------------------------
// Reg-staged bf16 GEMM, 128x128 tile with bias+gelu epilogue (FFN1).
// ---------------------------------------------------------------------------
__global__ __launch_bounds__(256) void gemm128_gelu(
    const ushort* __restrict__ A, const ushort* __restrict__ B,
    const float* __restrict__ bias, ushort* __restrict__ Cout,
    int M, int N, int K) {
  __shared__ ushort As[128 * 40];
  __shared__ ushort Bs[128 * 40];
  const int t = threadIdx.x;
  const int w = t >> 6, l = t & 63;
  const int lc = l & 15, lq = l >> 4;
  const int bm = blockIdx.y * 128, bn = blockIdx.x * 128;
  const int wr = (w >> 1) * 64, wc = (w & 1) * 64;
  const int sr = t >> 2, sk = (t & 3) * 8;

  f32x4 acc[4][4];
#pragma unroll
  for (int i = 0; i < 4; ++i)
#pragma unroll
    for (int j = 0; j < 4; ++j) acc[i][j] = (f32x4){0.f, 0.f, 0.f, 0.f};

  int4 a0v = *reinterpret_cast<const int4*>(A + (size_t)(bm + sr) * K + sk);
  int4 a1v = *reinterpret_cast<const int4*>(A + (size_t)(bm + 64 + sr) * K + sk);
  int4 b0v = *reinterpret_cast<const int4*>(B + (size_t)(bn + sr) * K + sk);
  int4 b1v = *reinterpret_cast<const int4*>(B + (size_t)(bn + 64 + sr) * K + sk);

  for (int k0 = 0; k0 < K; k0 += 32) {
    *reinterpret_cast<int4*>(As + sr * 40 + sk) = a0v;
    *reinterpret_cast<int4*>(As + (64 + sr) * 40 + sk) = a1v;
    *reinterpret_cast<int4*>(Bs + sr * 40 + sk) = b0v;
    *reinterpret_cast<int4*>(Bs + (64 + sr) * 40 + sk) = b1v;
    __syncthreads();
    if (k0 + 32 < K) {
      a0v = *reinterpret_cast<const int4*>(A + (size_t)(bm + sr) * K + k0 + 32 + sk);
      a1v = *reinterpret_cast<const int4*>(A + (size_t)(bm + 64 + sr) * K + k0 + 32 + sk);
      b0v = *reinterpret_cast<const int4*>(B + (size_t)(bn + sr) * K + k0 + 32 + sk);
      b1v = *reinterpret_cast<const int4*>(B + (size_t)(bn + 64 + sr) * K + k0 + 32 + sk);
    }
    short8_t af[4], bf[4];
#pragma unroll
    for (int mf = 0; mf < 4; ++mf)
      af[mf] = *reinterpret_cast<const short8_t*>(As + (wr + mf * 16 + lc) * 40 + lq * 8);
#pragma unroll
    for (int nf = 0; nf < 4; ++nf)
      bf[nf] = *reinterpret_cast<const short8_t*>(Bs + (wc + nf * 16 + lc) * 40 + lq * 8);
#pragma unroll
    for (int mf = 0; mf < 4; ++mf)
#pragma unroll
      for (int nf = 0; nf < 4; ++nf)
        acc[mf][nf] = __builtin_amdgcn_mfma_f32_16x16x32_bf16(af[mf], bf[nf], acc[mf][nf], 0, 0, 0);
    __syncthreads();
  }

#pragma unroll
  for (int mf = 0; mf < 4; ++mf)
#pragma unroll
    for (int nf = 0; nf < 4; ++nf) {
      const int col = bn + wc + nf * 16 + lc;
#pragma unroll
      for (int reg = 0; reg < 4; ++reg) {
        const int row = bm + wr + mf * 16 + lq * 4 + reg;
        float v = acc[mf][nf][reg] + bias[col];
        v = 0.5f * v * (1.0f + erff(v * 0.70710678118654752f));
        Cout[(size_t)row * N + col] = f2b(v);
      }
    }
}

// ---------------------------------------------------------------------------
// K-split reg-staged GEMM, 64x128 tile, f32 partial out (no bias).
// ---------------------------------------------------------------------------
__global__ __launch_bounds__(256) void gemm_split(
    const ushort* __restrict__ A, const ushort* __restrict__ B,
    float* __restrict__ Cout, int M, int N, int K, int halfK) {
  __shared__ ushort As[64 * 40];
  __shared__ ushort Bs[128 * 40];
  const int t = threadIdx.x;
  const int w = t >> 6, l = t & 63;
  const int lc = l & 15, lq = l >> 4;
  const int bm = blockIdx.y * 64, bn = blockIdx.x * 128;
  const int wr = (w >> 1) * 32, wc = (w & 1) * 64;
  const int sr = t >> 2, sk = (t & 3) * 8;
  const int kbeg = blockIdx.z * halfK, kend = kbeg + halfK;
  float* C = Cout + (size_t)blockIdx.z * M * N;

  f32x4 acc[2][4];
#pragma unroll
  for (int i = 0; i < 2; ++i)
#pragma unroll
    for (int j = 0; j < 4; ++j) acc[i][j] = (f32x4){0.f, 0.f, 0.f, 0.f};

  int4 a_v = *reinterpret_cast<const int4*>(A + (size_t)(bm + sr) * K + kbeg + sk);
  int4 b0v = *reinterpret_cast<const int4*>(B + (size_t)(bn + sr) * K + kbeg + sk);
  int4 b1v = *reinterpret_cast<const int4*>(B + (size_t)(bn + 64 + sr) * K + kbeg + sk);

  for (int k0 = kbeg; k0 < kend; k0 += 32) {
    *reinterpret_cast<int4*>(As + sr * 40 + sk) = a_v;
    *reinterpret_cast<int4*>(Bs + sr * 40 + sk) = b0v;
    *reinterpret_cast<int4*>(Bs + (64 + sr) * 40 + sk) = b1v;
    __syncthreads();
    if (k0 + 32 < kend) {
      a_v = *reinterpret_cast<const int4*>(A + (size_t)(bm + sr) * K + k0 + 32 + sk);
      b0v = *reinterpret_cast<const int4*>(B + (size_t)(bn + sr) * K + k0 + 32 + sk);
      b1v = *reinterpret_cast<const int4*>(B + (size_t)(bn + 64 + sr) * K + k0 + 32 + sk);
    }
    short8_t af[2], bf[4];
#pragma unroll
    for (int mf = 0; mf < 2; ++mf)
      af[mf] = *reinterpret_cast<const short8_t*>(As + (wr + mf * 16 + lc) * 40 + lq * 8);
#pragma unroll
    for (int nf = 0; nf < 4; ++nf)
      bf[nf] = *reinterpret_cast<const short8_t*>(Bs + (wc + nf * 16 + lc) * 40 + lq * 8);
#pragma unroll
    for (int mf = 0; mf < 2; ++mf)
#pragma unroll
      for (int nf = 0; nf < 4; ++nf)
        acc[mf][nf] = __builtin_amdgcn_mfma_f32_16x16x32_bf16(af[mf], bf[nf], acc[mf][nf], 0, 0, 0);
    __syncthreads();
  }

#pragma unroll
  for (int mf = 0; mf < 2; ++mf)
#pragma unroll
    for (int nf = 0; nf < 4; ++nf) {
      const int col = bn + wc + nf * 16 + lc;
#pragma unroll
      for (int reg = 0; reg < 4; ++reg) {
        const int row = bm + wr + mf * 16 + lq * 4 + reg;
        C[(size_t)row * N + col] = acc[mf][nf][reg];
      }
    }
}

// ---------------------------------------------------------------------------
// Merged repack (blocks [0,3072)) + kprelF (blocks [3072,3600), 128 active).
// ---------------------------------------------------------------------------
__global__ __launch_bounds__(256) void repack_kernel(
    const ushort* __restrict__ qkv, const float* __restrict__ rwb,
    const float* __restrict__ rrb, const ushort* __restrict__ kprel,
    ushort* __restrict__ qaF, ushort* __restrict__ qbF,
    ushort* __restrict__ kF, ushort* __restrict__ vF,
    ushort* __restrict__ kprelF) {
  __shared__ ushort st[32][72];
  const int bid = blockIdx.x, t = threadIdx.x;
  const int l = t & 63, lc = l & 15, lq = l >> 4;

  if (bid >= 3072) {   // kprelF part (128 active threads)
    if (t < 128) {
      const int e = bid - 3072;          // e = m + 66*n
      const int m = e % 66, n = e / 66;
      const int kc = t >> 6;
      const int rho = m * 16 - 31 + lc;
      short8_t v;
      if (rho >= 0 && rho < 1024)
        v = *reinterpret_cast<const short8_t*>(kprel + (size_t)rho * 512 + n * 64 + kc * 32 + lq * 8);
      else
#pragma unroll
        for (int e2 = 0; e2 < 8; ++e2) v[e2] = 0;
      const size_t o = ((size_t)((n * 66 + m) * 2 + kc)) * 512 + l * 8;
      *reinterpret_cast<short8_t*>(kprelF + o) = v;
    }
    return;
  }

  const int tile = bid & 31, head = (bid >> 5) & 31, role = bid >> 10;
  const int b = head >> 3, n = head & 7;
  const int s0 = tile * 32;
  const int sec = (role == 0) ? 0 : (role == 1) ? 512 : 1024;
  {
    const int s = t >> 3, d8 = (t & 7) * 8;
    int4 rd = *reinterpret_cast<const int4*>(
        qkv + (size_t)((s0 + s) * 4 + b) * 1536 + sec + n * 64 + d8);
    *reinterpret_cast<int4*>(&st[s][d8]) = rd;
  }
  __syncthreads();
  if (role == 0) {
    const int f = t >> 6, sub = f >> 1, kc = f & 1;
    const int row = sub * 16 + lc, k = kc * 32 + lq * 8;
    short8_t qv = *reinterpret_cast<const short8_t*>(&st[row][k]);
    const float4 w0 = *reinterpret_cast<const float4*>(rwb + n * 64 + k);
    const float4 w1 = *reinterpret_cast<const float4*>(rwb + n * 64 + k + 4);
    const float4 u0 = *reinterpret_cast<const float4*>(rrb + n * 64 + k);
    const float4 u1 = *reinterpret_cast<const float4*>(rrb + n * 64 + k + 4);
    const float wv[8] = {w0.x, w0.y, w0.z, w0.w, w1.x, w1.y, w1.z, w1.w};
    const float uv[8] = {u0.x, u0.y, u0.z, u0.w, u1.x, u1.y, u1.z, u1.w};
    short8_t a_, b_;
#pragma unroll
    for (int e = 0; e < 8; ++e) {
      float q = b2f((ushort)qv[e]);
      a_[e] = (short)f2b(q + wv[e]);
      b_[e] = (short)f2b(q + uv[e]);
    }
    const size_t o = ((size_t)((head * 64 + tile * 2 + sub) * 2 + kc)) * 512 + l * 8;
    *reinterpret_cast<short8_t*>(qaF + o) = a_;
    *reinterpret_cast<short8_t*>(qbF + o) = b_;
  } else if (role == 1) {
    const int f = t >> 6, sub = f >> 1, kc = f & 1;
    const int row = sub * 16 + lc, k = kc * 32 + lq * 8;
    short8_t kv = *reinterpret_cast<const short8_t*>(&st[row][k]);
    const size_t o = ((size_t)((head * 64 + tile * 2 + sub) * 2 + kc)) * 512 + l * 8;
    *reinterpret_cast<short8_t*>(kF + o) = kv;
  } else {
    const int nf = t >> 6;
    short8_t vv;
#pragma unroll
    for (int e = 0; e < 8; ++e) vv[e] = (short)st[lq * 8 + e][nf * 16 + lc];
    const size_t o = ((size_t)((head * 32 + tile) * 4 + nf)) * 512 + l * 8;
    *reinterpret_cast<short8_t*>(vF + o) = vv;
  }
}

// ---------------------------------------------------------------------------
// MFMA flash attention: 16-row i-tiles x 32-col j-tiles, triangle-paired,
// fragment-linear inputs, XCD-aware head grouping, defer-max + deferred-l
// softmax, and G diagonal gather via ds_bpermute (NO LDS roundtrip):
// value G[r][u] lives in frag u>>4, lane (u&15)|((r>>2)<<4), reg r&3.
// For reader row r=lq*4+j: u0=r-lc+31, u1=r-lc+15 share source lane
// sl=((r+15-lc)&15)|(lq<<4) and reg j; frag select by (r<=lc).
// LDS: P only, 4x16x40 u16 = 5120 B (merge buffers aliased in).
// ---------------------------------------------------------------------------
__global__ __launch_bounds__(256, 4) void attn_mfma(
    const ushort* __restrict__ qaF, const ushort* __restrict__ qbF,
    const ushort* __restrict__ kF, const ushort* __restrict__ kpF,
    const ushort* __restrict__ vF, ushort* __restrict__ av) {
  __shared__ __align__(16) char smemU[5120];

  const int t = threadIdx.x, w = t >> 6, l = t & 63;
  const int lid = blockIdx.y * 32 + blockIdx.x;
  const int head = (lid & 7) * 4 + ((lid >> 3) & 3);     // lid%8 -> XCD slot
  const int pr   = lid >> 5;
  const int b = head >> 3, n = head & 7;
  const int lc = l & 15, lq = l >> 4;

  ushort* pw = reinterpret_cast<ushort*>(smemU) + w * (16 * 40);

  for (int ph = 0; ph < 2; ++ph) {
    const int it = ph ? 63 - pr : pr;
    const int i0 = it * 16;
    __syncthreads();   // protect LDS from previous phase

    short8_t qa[2], qb[2];
    {
      const size_t qo = ((size_t)(head * 64 + it) * 2) * 512 + l * 8;
      qa[0] = *reinterpret_cast<const short8_t*>(qaF + qo);
      qa[1] = *reinterpret_cast<const short8_t*>(qaF + qo + 512);
      qb[0] = *reinterpret_cast<const short8_t*>(qbF + qo);
      qb[1] = *reinterpret_cast<const short8_t*>(qbF + qo + 512);
    }

    float m_run[4], l_lane[4];
    f32x4 oacc[4];
#pragma unroll
    for (int reg = 0; reg < 4; ++reg) { m_run[reg] = -1e30f; l_lane[reg] = 0.f; }
#pragma unroll
    for (int nf = 0; nf < 4; ++nf) oacc[nf] = (f32x4){0.f, 0.f, 0.f, 0.f};

    const int nj = it / 2 + 1;

    for (int jt = w; jt < nj; jt += 4) {
      const int j0 = jt * 32;
      const int D = i0 - j0;

      f32x4 sacc[2];
#pragma unroll
      for (int nf = 0; nf < 2; ++nf) sacc[nf] = (f32x4){0.f, 0.f, 0.f, 0.f};
#pragma unroll
      for (int kc = 0; kc < 2; ++kc)
#pragma unroll
        for (int nf = 0; nf < 2; ++nf) {
          short8_t kf = *reinterpret_cast<const short8_t*>(
              kF + ((size_t)((head * 64 + (j0 >> 4) + nf) * 2 + kc)) * 512 + l * 8);
          sacc[nf] = __builtin_amdgcn_mfma_f32_16x16x32_bf16(qa[kc], kf, sacc[nf], 0, 0, 0);
        }

      f32x4 gacc[3];
#pragma unroll
      for (int nf = 0; nf < 3; ++nf) gacc[nf] = (f32x4){0.f, 0.f, 0.f, 0.f};
#pragma unroll
      for (int kc = 0; kc < 2; ++kc)
#pragma unroll
        for (int nf = 0; nf < 3; ++nf) {
          short8_t pf = *reinterpret_cast<const short8_t*>(
              kpF + ((size_t)((n * 66 + (D >> 4) + nf) * 2 + kc)) * 512 + l * 8);
          gacc[nf] = __builtin_amdgcn_mfma_f32_16x16x32_bf16(qb[kc], pf, gacc[nf], 0, 0, 0);
        }

      // ---- G diagonal gather via ds_bpermute (no LDS, no barrier)
      float s0v[4], s1v[4];
#pragma unroll
      for (int j = 0; j < 4; ++j) {
        const int r = lq * 4 + j;
        const int sl4 = ((((r + 15 - lc) & 15) | (lq << 4)) << 2);
        const float g0 = __int_as_float(__builtin_amdgcn_ds_bpermute(sl4, __float_as_int(gacc[0][j])));
        const float g1 = __int_as_float(__builtin_amdgcn_ds_bpermute(sl4, __float_as_int(gacc[1][j])));
        const float g2 = __int_as_float(__builtin_amdgcn_ds_bpermute(sl4, __float_as_int(gacc[2][j])));
        const bool sel = (r <= lc);
        const float Gu0 = sel ? g1 : g2;
        const float Gu1 = sel ? g0 : g1;
        float s0 = (sacc[0][j] + Gu0) * 0.125f;
        float s1 = (sacc[1][j] + Gu1) * 0.125f;
        if (D < 32) {
          if (lc > D + r) s0 = -1e30f;
          if (16 + lc > D + r) s1 = -1e30f;
        }
        s0v[j] = s0; s1v[j] = s1;
      }

      // ---- defer-max: common path has ZERO cross-lane ops
      bool ok = true;
#pragma unroll
      for (int reg = 0; reg < 4; ++reg)
        ok &= (fmaxf(s0v[reg], s1v[reg]) <= m_run[reg] + 8.0f);
      if (__all(ok ? 1 : 0)) {
#pragma unroll
        for (int reg = 0; reg < 4; ++reg) {
          const int r = lq * 4 + reg;
          const float p0 = __expf(s0v[reg] - m_run[reg]);
          const float p1 = __expf(s1v[reg] - m_run[reg]);
          l_lane[reg] += p0 + p1;
          pw[r * 40 + lc] = f2b(p0);
          pw[r * 40 + 16 + lc] = f2b(p1);
        }
      } else {
#pragma unroll
        for (int reg = 0; reg < 4; ++reg) {
          const int r = lq * 4 + reg;
          float tm = fmaxf(s0v[reg], s1v[reg]);
          tm = fmaxf(tm, __shfl_xor(tm, 1));
          tm = fmaxf(tm, __shfl_xor(tm, 2));
          tm = fmaxf(tm, __shfl_xor(tm, 4));
          tm = fmaxf(tm, __shfl_xor(tm, 8));
          const float mn = fmaxf(m_run[reg], tm);
          const float corr = __expf(m_run[reg] - mn);
          const float p0 = __expf(s0v[reg] - mn), p1 = __expf(s1v[reg] - mn);
          l_lane[reg] = l_lane[reg] * corr + (p0 + p1);
          m_run[reg] = mn;
#pragma unroll
          for (int nf = 0; nf < 4; ++nf) oacc[nf][reg] *= corr;
          pw[r * 40 + lc] = f2b(p0);
          pw[r * 40 + 16 + lc] = f2b(p1);
        }
      }

      short8_t pa = *reinterpret_cast<const short8_t*>(pw + lc * 40 + lq * 8);
#pragma unroll
      for (int nf = 0; nf < 4; ++nf) {
        short8_t vf = *reinterpret_cast<const short8_t*>(
            vF + ((size_t)((head * 32 + jt) * 4 + nf)) * 512 + l * 8);
        oacc[nf] = __builtin_amdgcn_mfma_f32_16x16x32_bf16(pa, vf, oacc[nf], 0, 0, 0);
      }
    }

    // ---- one 16-lane l-reduction per phase (deferred from the loop)
    float l_run[4];
#pragma unroll
    for (int reg = 0; reg < 4; ++reg) {
      float v = l_lane[reg];
      v += __shfl_xor(v, 1);
      v += __shfl_xor(v, 2);
      v += __shfl_xor(v, 4);
      v += __shfl_xor(v, 8);
      l_run[reg] = v;
    }

    __syncthreads();
    float* obuf = reinterpret_cast<float*>(smemU);          // 16*68 f32 = 4352 B
    float* mlb  = reinterpret_cast<float*>(smemU + 4352);   // 4*16*2 f32 = 512 B

    if (lc == 0) {
#pragma unroll
      for (int reg = 0; reg < 4; ++reg) {
        const int r = lq * 4 + reg;
        mlb[(w * 16 + r) * 2 + 0] = m_run[reg];
        mlb[(w * 16 + r) * 2 + 1] = l_run[reg];
      }
    }
    for (int i = t; i < 16 * 68; i += 256) obuf[i] = 0.f;
    __syncthreads();

    float scl[4];
#pragma unroll
    for (int reg = 0; reg < 4; ++reg) {
      const int r = lq * 4 + reg;
      const float m0 = mlb[r * 2], m1 = mlb[(16 + r) * 2],
                  m2 = mlb[(32 + r) * 2], m3 = mlb[(48 + r) * 2];
      const float ms = fmaxf(fmaxf(m0, m1), fmaxf(m2, m3));
      scl[reg] = __expf(mlb[(w * 16 + r) * 2] - ms);
    }
#pragma unroll
    for (int ww = 0; ww < 4; ++ww) {
      if (w == ww) {
#pragma unroll
        for (int nf = 0; nf < 4; ++nf)
#pragma unroll
          for (int reg = 0; reg < 4; ++reg) {
            const int r = lq * 4 + reg;
            obuf[r * 68 + nf * 16 + lc] += scl[reg] * oacc[nf][reg];
          }
      }
      __syncthreads();
    }

    {
      const int r = t >> 4, d0 = (t & 15) * 4;
      const float m0 = mlb[r * 2], m1 = mlb[(16 + r) * 2],
                  m2 = mlb[(32 + r) * 2], m3 = mlb[(48 + r) * 2];
      const float ms = fmaxf(fmaxf(m0, m1), fmaxf(m2, m3));
      const float ls = mlb[r * 2 + 1] * __expf(m0 - ms) + mlb[(16 + r) * 2 + 1] * __expf(m1 - ms) +
                       mlb[(32 + r) * 2 + 1] * __expf(m2 - ms) + mlb[(48 + r) * 2 + 1] * __expf(m3 - ms);
      const float inv = 1.f / ls;
      uint pk0 = (uint)f2b(obuf[r * 68 + d0] * inv) | ((uint)f2b(obuf[r * 68 + d0 + 1] * inv) << 16);
      uint pk1 = (uint)f2b(obuf[r * 68 + d0 + 2] * inv) | ((uint)f2b(obuf[r * 68 + d0 + 3] * inv) << 16);
      int2 st2; st2.x = (int)pk0; st2.y = (int)pk1;
      const int tok = (i0 + r) * 4 + b;
      *reinterpret_cast<int2*>(av + (size_t)tok * 512 + n * 64 + d0) = st2;
    }
  }
}

// ---------------------------------------------------------------------------
// LayerNorm kernels (f32 math). ln_res sums two o-proj K-split partials +
// residual; ln_final sums two FFN2 partials + b2 + residual, then final LN.
// ---------------------------------------------------------------------------
__device__ __forceinline__ float blk_sum(float v, volatile float* sb) {
  v += __shfl_xor(v, 1);  v += __shfl_xor(v, 2);  v += __shfl_xor(v, 4);
  v += __shfl_xor(v, 8);  v += __shfl_xor(v, 16); v += __shfl_xor(v, 32);
  const int t = threadIdx.x;
  if ((t & 63) == 0) sb[t >> 6] = v;
  __syncthreads();
  v = sb[0] + sb[1] + sb[2] + sb[3];
  __syncthreads();
  return v;
}

__global__ __launch_bounds__(256) void ln_res_kernel(
    const float* __restrict__ aoa, const float* __restrict__ aob,
    const float* __restrict__ res,
    const float* __restrict__ g, const float* __restrict__ be,
    float* __restrict__ out, ushort* __restrict__ outb) {
  __shared__ float sb[4];
  const int row = blockIdx.x, t = threadIdx.x;
  const size_t base = (size_t)row * DM;
  const float x0 = aoa[base + t] + aob[base + t] + res[base + t];
  const float x1 = aoa[base + t + 256] + aob[base + t + 256] + res[base + t + 256];
  const float mu = blk_sum(x0 + x1, sb) * (1.f / DM);
  const float d0 = x0 - mu, d1 = x1 - mu;
  const float var = blk_sum(d0 * d0 + d1 * d1, sb) * (1.f / DM);
  const float inv = rsqrtf(var + LN_EPS);
  const float z0 = d0 * inv * g[t] + be[t];
  const float z1 = d1 * inv * g[t + 256] + be[t + 256];
  out[base + t] = z0;
  out[base + t + 256] = z1;
  outb[base + t] = f2b(z0);
  outb[base + t + 256] = f2b(z1);
}

__global__ __launch_bounds__(256) void ln_final_kernel(
    const float* __restrict__ ya, const float* __restrict__ yb,
    const float* __restrict__ b2, const float* __restrict__ xres,
    const float* __restrict__ g2, const float* __restrict__ be2,
    const float* __restrict__ gf, const float* __restrict__ bf,
    float* __restrict__ out) {
  __shared__ float sb[4];
  const int row = blockIdx.x, t = threadIdx.x;
  const size_t base = (size_t)row * DM;
  const float x0 = ya[base + t] + yb[base + t] + b2[t] + xres[base + t];
  const float x1 = ya[base + t + 256] + yb[base + t + 256] + b2[t + 256] + xres[base + t + 256];
  const float mu = blk_sum(x0 + x1, sb) * (1.f / DM);
  const float d0 = x0 - mu, d1 = x1 - mu;
  const float var = blk_sum(d0 * d0 + d1 * d1, sb) * (1.f / DM);
  const float inv = rsqrtf(var + LN_EPS);
  const float z0 = d0 * inv * g2[t] + be2[t];
  const float z1 = d1 * inv * g2[t + 256] + be2[t + 256];
  const float mu2 = blk_sum(z0 + z1, sb) * (1.f / DM);
  const float e0 = z0 - mu2, e1 = z1 - mu2;
  const float var2 = blk_sum(e0 * e0 + e1 * e1, sb) * (1.f / DM);
  const float inv2 = rsqrtf(var2 + LN_EPS);
  out[base + t]       = e0 * inv2 * gf[t] + bf[t];
  out[base + t + 256] = e1 * inv2 * gf[t + 256] + bf[t + 256];
}

// ---------------------------------------------------------------------------
extern "C" void kernel_launch(void* const* d_in, const int* in_sizes, int n_in,
                              void* d_out, int out_size, void* d_ws, size_t ws_size,
                              hipStream_t stream) {
  const float* src = (const float*)d_in[0];
  const float* q_w = (const float*)d_in[1];
  const float* k_w = (const float*)d_in[2];
  const float* v_w = (const float*)d_in[3];
  const float* r_w = (const float*)d_in[4];
  const float* o_w = (const float*)d_in[5];
  const float* rwb = (const float*)d_in[6];
  const float* rrb = (const float*)d_in[7];
  const float* w1  = (const float*)d_in[8];
  const float* b1  = (const float*)d_in[9];
  const float* w2  = (const float*)d_in[10];
  const float* b2  = (const float*)d_in[11];
  const float* g1  = (const float*)d_in[12];
  const float* be1 = (const float*)d_in[13];
  const float* g2  = (const float*)d_in[14];
  const float* be2 = (const float*)d_in[15];
  const float* gf  = (const float*)d_in[16];
  const float* bf  = (const float*)d_in[17];

  char* ws = (char*)d_ws;
  const size_t KB = 1024, MB = 1024 * 1024;
  ushort* srcb   = (ushort*)(ws);                        // 0    - 4 MB
  ushort* qkvw   = (ushort*)(ws + 4 * MB);               // 4    - 5.5
  ushort* rwT    = (ushort*)(ws + 5 * MB + 512 * KB);    // 5.5  - 6
  ushort* owb    = (ushort*)(ws + 6 * MB);               // 6    - 6.5
  ushort* w1b    = (ushort*)(ws + 6 * MB + 512 * KB);    // 6.5  - 8.5
  ushort* w2b    = (ushort*)(ws + 8 * MB + 512 * KB);    // 8.5  - 10.5
  ushort* peb    = (ushort*)(ws + 10 * MB + 512 * KB);   // 10.5 - 11.5
  ushort* qkv    = (ushort*)(ws + 11 * MB + 512 * KB);   // 11.5 - 23.5
  ushort* kprel  = (ushort*)(ws + 23 * MB + 512 * KB);   // 23.5 - 24.5
  ushort* qaF    = (ushort*)(ws + 24 * MB + 512 * KB);   // 24.5 - 28.5
  ushort* qbF    = (ushort*)(ws + 28 * MB + 512 * KB);   // 28.5 - 32.5
  ushort* kF     = (ushort*)(ws + 32 * MB + 512 * KB);   // 32.5 - 36.5
  ushort* vF     = (ushort*)(ws + 36 * MB + 512 * KB);   // 36.5 - 40.5
  ushort* kprelF = (ushort*)(ws + 40 * MB + 512 * KB);   // 40.5 - 41.6 (66 slots)
  ushort* av     = (ushort*)(ws + 42 * MB);              // 42   - 46
  float*  aoP    = (float*) (ws + 24 * MB + 512 * KB);   // 24.5 - 40.5 (2x8MB, over qaF..vF, dead after attn)
  float*  x1     = (float*) (ws + 46 * MB);              // 46   - 54
  ushort* x1b    = (ushort*)(ws + 42 * MB);              // 42   - 46 (over av, dead after o-proj)
  ushort* h      = (ushort*)(ws + 11 * MB + 512 * KB);   // 11.5 - 27.5 (qkv/kprel/aoP-head dead)
  float*  y2P    = (float*) (ws + 27 * MB + 512 * KB);   // 27.5 - 43.5 (2x8MB, aoP-tail/kprelF/x1b dead)
  float*  outp   = (float*)d_out;

  // fused preprocessing (pe + 4 cvt + weight transpose)
  prep_kernel<<<dim3(5248), 256, 0, stream>>>(src, o_w, w1, w2, q_w, k_w, v_w, r_w,
                                              peb, srcb, owb, w1b, w2b, qkvw, rwT);

  // fused QKV + kprel projections (one dispatch)
  gemm128_dual<<<dim3(416), 256, 0, stream>>>(srcb, qkvw, peb, rwT, qkv, kprel);

  // fused fragment-linear repack + kprelF
  repack_kernel<<<dim3(3600), 256, 0, stream>>>(qkv, rwb, rrb, kprel, qaF, qbF, kF, vF, kprelF);

  attn_mfma<<<dim3(32, 32), 256, 0, stream>>>(qaF, qbF, kF, kprelF, vF, av);

  // o-proj K-split x2 -> f32 partials; summed in ln_res
  gemm_split<<<dim3(4, 64, 2), 256, 0, stream>>>(av, owb, aoP, 4096, 512, 512, 256);
  ln_res_kernel<<<dim3(4096), 256, 0, stream>>>(aoP, aoP + 2097152, src, g1, be1, x1, x1b);

  gemm128_gelu<<<dim3(16, 32), 256, 0, stream>>>(x1b, w1b, b1, h, 4096, 2048, 512);
  // FFN2 K-split x2 -> f32 partials; summed (+b2) in ln_final
  gemm_split<<<dim3(4, 64, 2), 256, 0, stream>>>(h, w2b, y2P, 4096, 512, 2048, 1024);

  ln_final_kernel<<<dim3(4096), 256, 0, stream>>>(y2P, y2P + 2097152, b2, x1, g2, be2, gf, bf, outp);
}

// Round 19
// 132.939 us; speedup vs baseline: 1.6608x; 1.0089x over previous
//
#include <hip/hip_runtime.h>

#define QLEN 1024
#define BSZ  4
#define DM   512
#define NH   8
#define DH   64
#define FFD  2048

static constexpr float LN_EPS = 1e-5f;

typedef __attribute__((ext_vector_type(8))) short short8_t;  // 8 bf16 (4 VGPRs)
typedef __attribute__((ext_vector_type(4))) float f32x4;

__device__ __forceinline__ ushort f2b(float f) {
  uint u = __float_as_uint(f);
  return (ushort)((u + 0x7FFFu + ((u >> 16) & 1u)) >> 16);   // RNE
}
__device__ __forceinline__ float b2f(ushort h) {
  return __uint_as_float(((uint)h) << 16);
}

// ---------------------------------------------------------------------------
// Fused preprocessing: pe (2048 blk) | cvt src (1024) | cvt o_w (128) |
// cvt w1 (512) | cvt w2 (512) | trans512 (1024). Grid 5248 x 256.
// ---------------------------------------------------------------------------
__device__ __forceinline__ void cvt8_body(const float* in, ushort* out, int idx) {
  const float4 f0 = *reinterpret_cast<const float4*>(in + (size_t)idx * 8);
  const float4 f1 = *reinterpret_cast<const float4*>(in + (size_t)idx * 8 + 4);
  uint p0 = f2b(f0.x) | ((uint)f2b(f0.y) << 16);
  uint p1 = f2b(f0.z) | ((uint)f2b(f0.w) << 16);
  uint p2 = f2b(f1.x) | ((uint)f2b(f1.y) << 16);
  uint p3 = f2b(f1.z) | ((uint)f2b(f1.w) << 16);
  int4 st; st.x = (int)p0; st.y = (int)p1; st.z = (int)p2; st.w = (int)p3;
  *reinterpret_cast<int4*>(out + (size_t)idx * 8) = st;
}

__global__ __launch_bounds__(256) void prep_kernel(
    const float* __restrict__ src, const float* __restrict__ o_w,
    const float* __restrict__ w1, const float* __restrict__ w2,
    const float* __restrict__ qw, const float* __restrict__ kw,
    const float* __restrict__ vw, const float* __restrict__ rw,
    ushort* __restrict__ peb, ushort* __restrict__ srcb,
    ushort* __restrict__ owb, ushort* __restrict__ w1b,
    ushort* __restrict__ w2b, ushort* __restrict__ qkvw,
    ushort* __restrict__ rwT) {
  __shared__ float tile[32][33];
  const int bid = blockIdx.x, t = threadIdx.x;
  if (bid < 2048) {
    const int idx = bid * 256 + t;
    const int r = idx >> 9, f = idx & 511, f0 = f & 255;
    float invf = __expf(-(float)f0 * (9.210340371976184f / 256.0f));
    float arg  = (float)r * invf;
    peb[idx] = f2b((f < 256) ? __sinf(arg) : __cosf(arg));
  } else if (bid < 3072) {
    cvt8_body(src, srcb, (bid - 2048) * 256 + t);
  } else if (bid < 3200) {
    cvt8_body(o_w, owb, (bid - 3072) * 256 + t);
  } else if (bid < 3712) {
    cvt8_body(w1, w1b, (bid - 3200) * 256 + t);
  } else if (bid < 4224) {
    cvt8_body(w2, w2b, (bid - 3712) * 256 + t);
  } else {
    const int e = bid - 4224;
    const int z = e >> 8, rem = e & 255, bx = rem & 15, by = rem >> 4;
    const float* in = (z == 0) ? qw : (z == 1) ? kw : (z == 2) ? vw : rw;
    const int nd0 = bx * 32, h0 = by * 32;
    const int tx = t & 31, ty = t >> 5;
#pragma unroll
    for (int k = 0; k < 4; ++k)
      tile[ty + 8 * k][tx] = in[(size_t)(h0 + ty + 8 * k) * 512 + nd0 + tx];
    __syncthreads();
    ushort* out = (z < 3) ? (qkvw + (size_t)z * 512 * 512) : rwT;
#pragma unroll
    for (int k = 0; k < 4; ++k)
      out[(size_t)(nd0 + ty + 8 * k) * 512 + h0 + tx] = f2b(tile[tx][ty + 8 * k]);
  }
}

// ---------------------------------------------------------------------------
// 128x128 reg-staged GEMM body (bf16 out), shared by QKV and kprel.
// ---------------------------------------------------------------------------
__device__ __forceinline__ void gemm128_body(
    const ushort* A, const ushort* B, ushort* C,
    int N, int K, int bm, int bn, int t,
    ushort* As, ushort* Bs) {
  const int w = t >> 6, l = t & 63;
  const int lc = l & 15, lq = l >> 4;
  const int wr = (w >> 1) * 64, wc = (w & 1) * 64;
  const int sr = t >> 2, sk = (t & 3) * 8;

  f32x4 acc[4][4];
#pragma unroll
  for (int i = 0; i < 4; ++i)
#pragma unroll
    for (int j = 0; j < 4; ++j) acc[i][j] = (f32x4){0.f, 0.f, 0.f, 0.f};

  int4 a0v = *reinterpret_cast<const int4*>(A + (size_t)(bm + sr) * K + sk);
  int4 a1v = *reinterpret_cast<const int4*>(A + (size_t)(bm + 64 + sr) * K + sk);
  int4 b0v = *reinterpret_cast<const int4*>(B + (size_t)(bn + sr) * K + sk);
  int4 b1v = *reinterpret_cast<const int4*>(B + (size_t)(bn + 64 + sr) * K + sk);

  for (int k0 = 0; k0 < K; k0 += 32) {
    *reinterpret_cast<int4*>(As + sr * 40 + sk) = a0v;
    *reinterpret_cast<int4*>(As + (64 + sr) * 40 + sk) = a1v;
    *reinterpret_cast<int4*>(Bs + sr * 40 + sk) = b0v;
    *reinterpret_cast<int4*>(Bs + (64 + sr) * 40 + sk) = b1v;
    __syncthreads();
    if (k0 + 32 < K) {
      a0v = *reinterpret_cast<const int4*>(A + (size_t)(bm + sr) * K + k0 + 32 + sk);
      a1v = *reinterpret_cast<const int4*>(A + (size_t)(bm + 64 + sr) * K + k0 + 32 + sk);
      b0v = *reinterpret_cast<const int4*>(B + (size_t)(bn + sr) * K + k0 + 32 + sk);
      b1v = *reinterpret_cast<const int4*>(B + (size_t)(bn + 64 + sr) * K + k0 + 32 + sk);
    }
    short8_t af[4], bf[4];
#pragma unroll
    for (int mf = 0; mf < 4; ++mf)
      af[mf] = *reinterpret_cast<const short8_t*>(As + (wr + mf * 16 + lc) * 40 + lq * 8);
#pragma unroll
    for (int nf = 0; nf < 4; ++nf)
      bf[nf] = *reinterpret_cast<const short8_t*>(Bs + (wc + nf * 16 + lc) * 40 + lq * 8);
#pragma unroll
    for (int mf = 0; mf < 4; ++mf)
#pragma unroll
      for (int nf = 0; nf < 4; ++nf)
        acc[mf][nf] = __builtin_amdgcn_mfma_f32_16x16x32_bf16(af[mf], bf[nf], acc[mf][nf], 0, 0, 0);
    __syncthreads();
  }

#pragma unroll
  for (int mf = 0; mf < 4; ++mf)
#pragma unroll
    for (int nf = 0; nf < 4; ++nf) {
      const int col = bn + wc + nf * 16 + lc;
#pragma unroll
      for (int reg = 0; reg < 4; ++reg) {
        const int row = bm + wr + mf * 16 + lq * 4 + reg;
        C[(size_t)row * N + col] = f2b(acc[mf][nf][reg]);
      }
    }
}

// Dual launch: blocks [0,384) = QKV (4096x1536x512); [384,416) = kprel
// (1024x512x512). One dispatch fills the machine, removes a launch gap.
__global__ __launch_bounds__(256) void gemm128_dual(
    const ushort* __restrict__ srcb, const ushort* __restrict__ qkvw,
    const ushort* __restrict__ peb, const ushort* __restrict__ rwT,
    ushort* __restrict__ qkv, ushort* __restrict__ kprel) {
  __shared__ ushort As[128 * 40];
  __shared__ ushort Bs[128 * 40];
  const int bid = blockIdx.x, t = threadIdx.x;
  if (bid < 384) {
    const int bx = bid % 12, by = bid / 12;
    gemm128_body(srcb, qkvw, qkv, 1536, 512, by * 128, bx * 128, t, As, Bs);
  } else {
    const int e = bid - 384;
    const int bx = e & 3, by = e >> 2;
    gemm128_body(peb, rwT, kprel, 512, 512, by * 128, bx * 128, t, As, Bs);
  }
}

// ---------------------------------------------------------------------------
// Reg-staged bf16 GEMM, 128x128 tile with bias+gelu epilogue (FFN1).
// ---------------------------------------------------------------------------
__global__ __launch_bounds__(256) void gemm128_gelu(
    const ushort* __restrict__ A, const ushort* __restrict__ B,
    const float* __restrict__ bias, ushort* __restrict__ Cout,
    int M, int N, int K) {
  __shared__ ushort As[128 * 40];
  __shared__ ushort Bs[128 * 40];
  const int t = threadIdx.x;
  const int w = t >> 6, l = t & 63;
  const int lc = l & 15, lq = l >> 4;
  const int bm = blockIdx.y * 128, bn = blockIdx.x * 128;
  const int wr = (w >> 1) * 64, wc = (w & 1) * 64;
  const int sr = t >> 2, sk = (t & 3) * 8;

  f32x4 acc[4][4];
#pragma unroll
  for (int i = 0; i < 4; ++i)
#pragma unroll
    for (int j = 0; j < 4; ++j) acc[i][j] = (f32x4){0.f, 0.f, 0.f, 0.f};

  int4 a0v = *reinterpret_cast<const int4*>(A + (size_t)(bm + sr) * K + sk);
  int4 a1v = *reinterpret_cast<const int4*>(A + (size_t)(bm + 64 + sr) * K + sk);
  int4 b0v = *reinterpret_cast<const int4*>(B + (size_t)(bn + sr) * K + sk);
  int4 b1v = *reinterpret_cast<const int4*>(B + (size_t)(bn + 64 + sr) * K + sk);

  for (int k0 = 0; k0 < K; k0 += 32) {
    *reinterpret_cast<int4*>(As + sr * 40 + sk) = a0v;
    *reinterpret_cast<int4*>(As + (64 + sr) * 40 + sk) = a1v;
    *reinterpret_cast<int4*>(Bs + sr * 40 + sk) = b0v;
    *reinterpret_cast<int4*>(Bs + (64 + sr) * 40 + sk) = b1v;
    __syncthreads();
    if (k0 + 32 < K) {
      a0v = *reinterpret_cast<const int4*>(A + (size_t)(bm + sr) * K + k0 + 32 + sk);
      a1v = *reinterpret_cast<const int4*>(A + (size_t)(bm + 64 + sr) * K + k0 + 32 + sk);
      b0v = *reinterpret_cast<const int4*>(B + (size_t)(bn + sr) * K + k0 + 32 + sk);
      b1v = *reinterpret_cast<const int4*>(B + (size_t)(bn + 64 + sr) * K + k0 + 32 + sk);
    }
    short8_t af[4], bf[4];
#pragma unroll
    for (int mf = 0; mf < 4; ++mf)
      af[mf] = *reinterpret_cast<const short8_t*>(As + (wr + mf * 16 + lc) * 40 + lq * 8);
#pragma unroll
    for (int nf = 0; nf < 4; ++nf)
      bf[nf] = *reinterpret_cast<const short8_t*>(Bs + (wc + nf * 16 + lc) * 40 + lq * 8);
#pragma unroll
    for (int mf = 0; mf < 4; ++mf)
#pragma unroll
      for (int nf = 0; nf < 4; ++nf)
        acc[mf][nf] = __builtin_amdgcn_mfma_f32_16x16x32_bf16(af[mf], bf[nf], acc[mf][nf], 0, 0, 0);
    __syncthreads();
  }

#pragma unroll
  for (int mf = 0; mf < 4; ++mf)
#pragma unroll
    for (int nf = 0; nf < 4; ++nf) {
      const int col = bn + wc + nf * 16 + lc;
#pragma unroll
      for (int reg = 0; reg < 4; ++reg) {
        const int row = bm + wr + mf * 16 + lq * 4 + reg;
        float v = acc[mf][nf][reg] + bias[col];
        v = 0.5f * v * (1.0f + erff(v * 0.70710678118654752f));
        Cout[(size_t)row * N + col] = f2b(v);
      }
    }
}

// ---------------------------------------------------------------------------
// K-split reg-staged GEMM, 64x128 tile, f32 partial out (no bias).
// ---------------------------------------------------------------------------
__global__ __launch_bounds__(256) void gemm_split(
    const ushort* __restrict__ A, const ushort* __restrict__ B,
    float* __restrict__ Cout, int M, int N, int K, int halfK) {
  __shared__ ushort As[64 * 40];
  __shared__ ushort Bs[128 * 40];
  const int t = threadIdx.x;
  const int w = t >> 6, l = t & 63;
  const int lc = l & 15, lq = l >> 4;
  const int bm = blockIdx.y * 64, bn = blockIdx.x * 128;
  const int wr = (w >> 1) * 32, wc = (w & 1) * 64;
  const int sr = t >> 2, sk = (t & 3) * 8;
  const int kbeg = blockIdx.z * halfK, kend = kbeg + halfK;
  float* C = Cout + (size_t)blockIdx.z * M * N;

  f32x4 acc[2][4];
#pragma unroll
  for (int i = 0; i < 2; ++i)
#pragma unroll
    for (int j = 0; j < 4; ++j) acc[i][j] = (f32x4){0.f, 0.f, 0.f, 0.f};

  int4 a_v = *reinterpret_cast<const int4*>(A + (size_t)(bm + sr) * K + kbeg + sk);
  int4 b0v = *reinterpret_cast<const int4*>(B + (size_t)(bn + sr) * K + kbeg + sk);
  int4 b1v = *reinterpret_cast<const int4*>(B + (size_t)(bn + 64 + sr) * K + kbeg + sk);

  for (int k0 = kbeg; k0 < kend; k0 += 32) {
    *reinterpret_cast<int4*>(As + sr * 40 + sk) = a_v;
    *reinterpret_cast<int4*>(Bs + sr * 40 + sk) = b0v;
    *reinterpret_cast<int4*>(Bs + (64 + sr) * 40 + sk) = b1v;
    __syncthreads();
    if (k0 + 32 < kend) {
      a_v = *reinterpret_cast<const int4*>(A + (size_t)(bm + sr) * K + k0 + 32 + sk);
      b0v = *reinterpret_cast<const int4*>(B + (size_t)(bn + sr) * K + k0 + 32 + sk);
      b1v = *reinterpret_cast<const int4*>(B + (size_t)(bn + 64 + sr) * K + k0 + 32 + sk);
    }
    short8_t af[2], bf[4];
#pragma unroll
    for (int mf = 0; mf < 2; ++mf)
      af[mf] = *reinterpret_cast<const short8_t*>(As + (wr + mf * 16 + lc) * 40 + lq * 8);
#pragma unroll
    for (int nf = 0; nf < 4; ++nf)
      bf[nf] = *reinterpret_cast<const short8_t*>(Bs + (wc + nf * 16 + lc) * 40 + lq * 8);
#pragma unroll
    for (int mf = 0; mf < 2; ++mf)
#pragma unroll
      for (int nf = 0; nf < 4; ++nf)
        acc[mf][nf] = __builtin_amdgcn_mfma_f32_16x16x32_bf16(af[mf], bf[nf], acc[mf][nf], 0, 0, 0);
    __syncthreads();
  }

#pragma unroll
  for (int mf = 0; mf < 2; ++mf)
#pragma unroll
    for (int nf = 0; nf < 4; ++nf) {
      const int col = bn + wc + nf * 16 + lc;
#pragma unroll
      for (int reg = 0; reg < 4; ++reg) {
        const int row = bm + wr + mf * 16 + lq * 4 + reg;
        C[(size_t)row * N + col] = acc[mf][nf][reg];
      }
    }
}

// ---------------------------------------------------------------------------
// Merged repack (blocks [0,3072)) + kprelF (blocks [3072,3600), 128 active).
// ---------------------------------------------------------------------------
__global__ __launch_bounds__(256) void repack_kernel(
    const ushort* __restrict__ qkv, const float* __restrict__ rwb,
    const float* __restrict__ rrb, const ushort* __restrict__ kprel,
    ushort* __restrict__ qaF, ushort* __restrict__ qbF,
    ushort* __restrict__ kF, ushort* __restrict__ vF,
    ushort* __restrict__ kprelF) {
  __shared__ ushort st[32][72];
  const int bid = blockIdx.x, t = threadIdx.x;
  const int l = t & 63, lc = l & 15, lq = l >> 4;

  if (bid >= 3072) {   // kprelF part (128 active threads)
    if (t < 128) {
      const int e = bid - 3072;          // e = m + 66*n
      const int m = e % 66, n = e / 66;
      const int kc = t >> 6;
      const int rho = m * 16 - 31 + lc;
      short8_t v;
      if (rho >= 0 && rho < 1024)
        v = *reinterpret_cast<const short8_t*>(kprel + (size_t)rho * 512 + n * 64 + kc * 32 + lq * 8);
      else
#pragma unroll
        for (int e2 = 0; e2 < 8; ++e2) v[e2] = 0;
      const size_t o = ((size_t)((n * 66 + m) * 2 + kc)) * 512 + l * 8;
      *reinterpret_cast<short8_t*>(kprelF + o) = v;
    }
    return;
  }

  const int tile = bid & 31, head = (bid >> 5) & 31, role = bid >> 10;
  const int b = head >> 3, n = head & 7;
  const int s0 = tile * 32;
  const int sec = (role == 0) ? 0 : (role == 1) ? 512 : 1024;
  {
    const int s = t >> 3, d8 = (t & 7) * 8;
    int4 rd = *reinterpret_cast<const int4*>(
        qkv + (size_t)((s0 + s) * 4 + b) * 1536 + sec + n * 64 + d8);
    *reinterpret_cast<int4*>(&st[s][d8]) = rd;
  }
  __syncthreads();
  if (role == 0) {
    const int f = t >> 6, sub = f >> 1, kc = f & 1;
    const int row = sub * 16 + lc, k = kc * 32 + lq * 8;
    short8_t qv = *reinterpret_cast<const short8_t*>(&st[row][k]);
    const float4 w0 = *reinterpret_cast<const float4*>(rwb + n * 64 + k);
    const float4 w1 = *reinterpret_cast<const float4*>(rwb + n * 64 + k + 4);
    const float4 u0 = *reinterpret_cast<const float4*>(rrb + n * 64 + k);
    const float4 u1 = *reinterpret_cast<const float4*>(rrb + n * 64 + k + 4);
    const float wv[8] = {w0.x, w0.y, w0.z, w0.w, w1.x, w1.y, w1.z, w1.w};
    const float uv[8] = {u0.x, u0.y, u0.z, u0.w, u1.x, u1.y, u1.z, u1.w};
    short8_t a_, b_;
#pragma unroll
    for (int e = 0; e < 8; ++e) {
      float q = b2f((ushort)qv[e]);
      a_[e] = (short)f2b(q + wv[e]);
      b_[e] = (short)f2b(q + uv[e]);
    }
    const size_t o = ((size_t)((head * 64 + tile * 2 + sub) * 2 + kc)) * 512 + l * 8;
    *reinterpret_cast<short8_t*>(qaF + o) = a_;
    *reinterpret_cast<short8_t*>(qbF + o) = b_;
  } else if (role == 1) {
    const int f = t >> 6, sub = f >> 1, kc = f & 1;
    const int row = sub * 16 + lc, k = kc * 32 + lq * 8;
    short8_t kv = *reinterpret_cast<const short8_t*>(&st[row][k]);
    const size_t o = ((size_t)((head * 64 + tile * 2 + sub) * 2 + kc)) * 512 + l * 8;
    *reinterpret_cast<short8_t*>(kF + o) = kv;
  } else {
    const int nf = t >> 6;
    short8_t vv;
#pragma unroll
    for (int e = 0; e < 8; ++e) vv[e] = (short)st[lq * 8 + e][nf * 16 + lc];
    const size_t o = ((size_t)((head * 32 + tile) * 4 + nf)) * 512 + l * 8;
    *reinterpret_cast<short8_t*>(vF + o) = vv;
  }
}

// ---------------------------------------------------------------------------
// MFMA flash attention: 16-row i-tiles x 32-col j-tiles, triangle-paired,
// fragment-linear inputs, XCD-aware head grouping, defer-max + deferred-l
// softmax, ds_bpermute G gather, V ISSUE-EARLY (+16 VGPR live range: loads
// moved before the gather/softmax so their L2 latency hides under it), and
// s_setprio(1) around the MFMA clusters (independent-wave regime).
// LDS: P only, 4x16x40 u16 = 5120 B (merge buffers aliased in).
// ---------------------------------------------------------------------------
__global__ __launch_bounds__(256, 4) void attn_mfma(
    const ushort* __restrict__ qaF, const ushort* __restrict__ qbF,
    const ushort* __restrict__ kF, const ushort* __restrict__ kpF,
    const ushort* __restrict__ vF, ushort* __restrict__ av) {
  __shared__ __align__(16) char smemU[5120];

  const int t = threadIdx.x, w = t >> 6, l = t & 63;
  const int lid = blockIdx.y * 32 + blockIdx.x;
  const int head = (lid & 7) * 4 + ((lid >> 3) & 3);     // lid%8 -> XCD slot
  const int pr   = lid >> 5;
  const int b = head >> 3, n = head & 7;
  const int lc = l & 15, lq = l >> 4;

  ushort* pw = reinterpret_cast<ushort*>(smemU) + w * (16 * 40);

  for (int ph = 0; ph < 2; ++ph) {
    const int it = ph ? 63 - pr : pr;
    const int i0 = it * 16;
    __syncthreads();   // protect LDS from previous phase

    short8_t qa[2], qb[2];
    {
      const size_t qo = ((size_t)(head * 64 + it) * 2) * 512 + l * 8;
      qa[0] = *reinterpret_cast<const short8_t*>(qaF + qo);
      qa[1] = *reinterpret_cast<const short8_t*>(qaF + qo + 512);
      qb[0] = *reinterpret_cast<const short8_t*>(qbF + qo);
      qb[1] = *reinterpret_cast<const short8_t*>(qbF + qo + 512);
    }

    float m_run[4], l_lane[4];
    f32x4 oacc[4];
#pragma unroll
    for (int reg = 0; reg < 4; ++reg) { m_run[reg] = -1e30f; l_lane[reg] = 0.f; }
#pragma unroll
    for (int nf = 0; nf < 4; ++nf) oacc[nf] = (f32x4){0.f, 0.f, 0.f, 0.f};

    const int nj = it / 2 + 1;

    for (int jt = w; jt < nj; jt += 4) {
      const int j0 = jt * 32;
      const int D = i0 - j0;

      f32x4 sacc[2];
#pragma unroll
      for (int nf = 0; nf < 2; ++nf) sacc[nf] = (f32x4){0.f, 0.f, 0.f, 0.f};
      __builtin_amdgcn_s_setprio(1);
#pragma unroll
      for (int kc = 0; kc < 2; ++kc)
#pragma unroll
        for (int nf = 0; nf < 2; ++nf) {
          short8_t kf = *reinterpret_cast<const short8_t*>(
              kF + ((size_t)((head * 64 + (j0 >> 4) + nf) * 2 + kc)) * 512 + l * 8);
          sacc[nf] = __builtin_amdgcn_mfma_f32_16x16x32_bf16(qa[kc], kf, sacc[nf], 0, 0, 0);
        }

      f32x4 gacc[3];
#pragma unroll
      for (int nf = 0; nf < 3; ++nf) gacc[nf] = (f32x4){0.f, 0.f, 0.f, 0.f};
#pragma unroll
      for (int kc = 0; kc < 2; ++kc)
#pragma unroll
        for (int nf = 0; nf < 3; ++nf) {
          short8_t pf = *reinterpret_cast<const short8_t*>(
              kpF + ((size_t)((n * 66 + (D >> 4) + nf) * 2 + kc)) * 512 + l * 8);
          gacc[nf] = __builtin_amdgcn_mfma_f32_16x16x32_bf16(qb[kc], pf, gacc[nf], 0, 0, 0);
        }
      __builtin_amdgcn_s_setprio(0);

      // ---- V issue-early: loads for THIS iteration's PV, latency hidden
      // under the gather + softmax below (+16 VGPR live range, 80 << 128).
      short8_t vf0 = *reinterpret_cast<const short8_t*>(
          vF + ((size_t)((head * 32 + jt) * 4 + 0)) * 512 + l * 8);
      short8_t vf1 = *reinterpret_cast<const short8_t*>(
          vF + ((size_t)((head * 32 + jt) * 4 + 1)) * 512 + l * 8);
      short8_t vf2 = *reinterpret_cast<const short8_t*>(
          vF + ((size_t)((head * 32 + jt) * 4 + 2)) * 512 + l * 8);
      short8_t vf3 = *reinterpret_cast<const short8_t*>(
          vF + ((size_t)((head * 32 + jt) * 4 + 3)) * 512 + l * 8);

      // ---- G diagonal gather via ds_bpermute (no LDS, no barrier)
      float s0v[4], s1v[4];
#pragma unroll
      for (int j = 0; j < 4; ++j) {
        const int r = lq * 4 + j;
        const int sl4 = ((((r + 15 - lc) & 15) | (lq << 4)) << 2);
        const float g0 = __int_as_float(__builtin_amdgcn_ds_bpermute(sl4, __float_as_int(gacc[0][j])));
        const float g1 = __int_as_float(__builtin_amdgcn_ds_bpermute(sl4, __float_as_int(gacc[1][j])));
        const float g2 = __int_as_float(__builtin_amdgcn_ds_bpermute(sl4, __float_as_int(gacc[2][j])));
        const bool sel = (r <= lc);
        const float Gu0 = sel ? g1 : g2;
        const float Gu1 = sel ? g0 : g1;
        float s0 = (sacc[0][j] + Gu0) * 0.125f;
        float s1 = (sacc[1][j] + Gu1) * 0.125f;
        if (D < 32) {
          if (lc > D + r) s0 = -1e30f;
          if (16 + lc > D + r) s1 = -1e30f;
        }
        s0v[j] = s0; s1v[j] = s1;
      }

      // ---- defer-max: common path has ZERO cross-lane ops
      bool ok = true;
#pragma unroll
      for (int reg = 0; reg < 4; ++reg)
        ok &= (fmaxf(s0v[reg], s1v[reg]) <= m_run[reg] + 8.0f);
      if (__all(ok ? 1 : 0)) {
#pragma unroll
        for (int reg = 0; reg < 4; ++reg) {
          const int r = lq * 4 + reg;
          const float p0 = __expf(s0v[reg] - m_run[reg]);
          const float p1 = __expf(s1v[reg] - m_run[reg]);
          l_lane[reg] += p0 + p1;
          pw[r * 40 + lc] = f2b(p0);
          pw[r * 40 + 16 + lc] = f2b(p1);
        }
      } else {
#pragma unroll
        for (int reg = 0; reg < 4; ++reg) {
          const int r = lq * 4 + reg;
          float tm = fmaxf(s0v[reg], s1v[reg]);
          tm = fmaxf(tm, __shfl_xor(tm, 1));
          tm = fmaxf(tm, __shfl_xor(tm, 2));
          tm = fmaxf(tm, __shfl_xor(tm, 4));
          tm = fmaxf(tm, __shfl_xor(tm, 8));
          const float mn = fmaxf(m_run[reg], tm);
          const float corr = __expf(m_run[reg] - mn);
          const float p0 = __expf(s0v[reg] - mn), p1 = __expf(s1v[reg] - mn);
          l_lane[reg] = l_lane[reg] * corr + (p0 + p1);
          m_run[reg] = mn;
#pragma unroll
          for (int nf = 0; nf < 4; ++nf) oacc[nf][reg] *= corr;
          pw[r * 40 + lc] = f2b(p0);
          pw[r * 40 + 16 + lc] = f2b(p1);
        }
      }

      short8_t pa = *reinterpret_cast<const short8_t*>(pw + lc * 40 + lq * 8);
      __builtin_amdgcn_s_setprio(1);
      oacc[0] = __builtin_amdgcn_mfma_f32_16x16x32_bf16(pa, vf0, oacc[0], 0, 0, 0);
      oacc[1] = __builtin_amdgcn_mfma_f32_16x16x32_bf16(pa, vf1, oacc[1], 0, 0, 0);
      oacc[2] = __builtin_amdgcn_mfma_f32_16x16x32_bf16(pa, vf2, oacc[2], 0, 0, 0);
      oacc[3] = __builtin_amdgcn_mfma_f32_16x16x32_bf16(pa, vf3, oacc[3], 0, 0, 0);
      __builtin_amdgcn_s_setprio(0);
    }

    // ---- one 16-lane l-reduction per phase (deferred from the loop)
    float l_run[4];
#pragma unroll
    for (int reg = 0; reg < 4; ++reg) {
      float v = l_lane[reg];
      v += __shfl_xor(v, 1);
      v += __shfl_xor(v, 2);
      v += __shfl_xor(v, 4);
      v += __shfl_xor(v, 8);
      l_run[reg] = v;
    }

    __syncthreads();
    float* obuf = reinterpret_cast<float*>(smemU);          // 16*68 f32 = 4352 B
    float* mlb  = reinterpret_cast<float*>(smemU + 4352);   // 4*16*2 f32 = 512 B

    if (lc == 0) {
#pragma unroll
      for (int reg = 0; reg < 4; ++reg) {
        const int r = lq * 4 + reg;
        mlb[(w * 16 + r) * 2 + 0] = m_run[reg];
        mlb[(w * 16 + r) * 2 + 1] = l_run[reg];
      }
    }
    for (int i = t; i < 16 * 68; i += 256) obuf[i] = 0.f;
    __syncthreads();

    float scl[4];
#pragma unroll
    for (int reg = 0; reg < 4; ++reg) {
      const int r = lq * 4 + reg;
      const float m0 = mlb[r * 2], m1 = mlb[(16 + r) * 2],
                  m2 = mlb[(32 + r) * 2], m3 = mlb[(48 + r) * 2];
      const float ms = fmaxf(fmaxf(m0, m1), fmaxf(m2, m3));
      scl[reg] = __expf(mlb[(w * 16 + r) * 2] - ms);
    }
#pragma unroll
    for (int ww = 0; ww < 4; ++ww) {
      if (w == ww) {
#pragma unroll
        for (int nf = 0; nf < 4; ++nf)
#pragma unroll
          for (int reg = 0; reg < 4; ++reg) {
            const int r = lq * 4 + reg;
            obuf[r * 68 + nf * 16 + lc] += scl[reg] * oacc[nf][reg];
          }
      }
      __syncthreads();
    }

    {
      const int r = t >> 4, d0 = (t & 15) * 4;
      const float m0 = mlb[r * 2], m1 = mlb[(16 + r) * 2],
                  m2 = mlb[(32 + r) * 2], m3 = mlb[(48 + r) * 2];
      const float ms = fmaxf(fmaxf(m0, m1), fmaxf(m2, m3));
      const float ls = mlb[r * 2 + 1] * __expf(m0 - ms) + mlb[(16 + r) * 2 + 1] * __expf(m1 - ms) +
                       mlb[(32 + r) * 2 + 1] * __expf(m2 - ms) + mlb[(48 + r) * 2 + 1] * __expf(m3 - ms);
      const float inv = 1.f / ls;
      uint pk0 = (uint)f2b(obuf[r * 68 + d0] * inv) | ((uint)f2b(obuf[r * 68 + d0 + 1] * inv) << 16);
      uint pk1 = (uint)f2b(obuf[r * 68 + d0 + 2] * inv) | ((uint)f2b(obuf[r * 68 + d0 + 3] * inv) << 16);
      int2 st2; st2.x = (int)pk0; st2.y = (int)pk1;
      const int tok = (i0 + r) * 4 + b;
      *reinterpret_cast<int2*>(av + (size_t)tok * 512 + n * 64 + d0) = st2;
    }
  }
}

// ---------------------------------------------------------------------------
// LayerNorm kernels (f32 math). ln_res sums two o-proj K-split partials +
// residual; ln_final sums two FFN2 partials + b2 + residual, then final LN.
// ---------------------------------------------------------------------------
__device__ __forceinline__ float blk_sum(float v, volatile float* sb) {
  v += __shfl_xor(v, 1);  v += __shfl_xor(v, 2);  v += __shfl_xor(v, 4);
  v += __shfl_xor(v, 8);  v += __shfl_xor(v, 16); v += __shfl_xor(v, 32);
  const int t = threadIdx.x;
  if ((t & 63) == 0) sb[t >> 6] = v;
  __syncthreads();
  v = sb[0] + sb[1] + sb[2] + sb[3];
  __syncthreads();
  return v;
}

__global__ __launch_bounds__(256) void ln_res_kernel(
    const float* __restrict__ aoa, const float* __restrict__ aob,
    const float* __restrict__ res,
    const float* __restrict__ g, const float* __restrict__ be,
    float* __restrict__ out, ushort* __restrict__ outb) {
  __shared__ float sb[4];
  const int row = blockIdx.x, t = threadIdx.x;
  const size_t base = (size_t)row * DM;
  const float x0 = aoa[base + t] + aob[base + t] + res[base + t];
  const float x1 = aoa[base + t + 256] + aob[base + t + 256] + res[base + t + 256];
  const float mu = blk_sum(x0 + x1, sb) * (1.f / DM);
  const float d0 = x0 - mu, d1 = x1 - mu;
  const float var = blk_sum(d0 * d0 + d1 * d1, sb) * (1.f / DM);
  const float inv = rsqrtf(var + LN_EPS);
  const float z0 = d0 * inv * g[t] + be[t];
  const float z1 = d1 * inv * g[t + 256] + be[t + 256];
  out[base + t] = z0;
  out[base + t + 256] = z1;
  outb[base + t] = f2b(z0);
  outb[base + t + 256] = f2b(z1);
}

__global__ __launch_bounds__(256) void ln_final_kernel(
    const float* __restrict__ ya, const float* __restrict__ yb,
    const float* __restrict__ b2, const float* __restrict__ xres,
    const float* __restrict__ g2, const float* __restrict__ be2,
    const float* __restrict__ gf, const float* __restrict__ bf,
    float* __restrict__ out) {
  __shared__ float sb[4];
  const int row = blockIdx.x, t = threadIdx.x;
  const size_t base = (size_t)row * DM;
  const float x0 = ya[base + t] + yb[base + t] + b2[t] + xres[base + t];
  const float x1 = ya[base + t + 256] + yb[base + t + 256] + b2[t + 256] + xres[base + t + 256];
  const float mu = blk_sum(x0 + x1, sb) * (1.f / DM);
  const float d0 = x0 - mu, d1 = x1 - mu;
  const float var = blk_sum(d0 * d0 + d1 * d1, sb) * (1.f / DM);
  const float inv = rsqrtf(var + LN_EPS);
  const float z0 = d0 * inv * g2[t] + be2[t];
  const float z1 = d1 * inv * g2[t + 256] + be2[t + 256];
  const float mu2 = blk_sum(z0 + z1, sb) * (1.f / DM);
  const float e0 = z0 - mu2, e1 = z1 - mu2;
  const float var2 = blk_sum(e0 * e0 + e1 * e1, sb) * (1.f / DM);
  const float inv2 = rsqrtf(var2 + LN_EPS);
  out[base + t]       = e0 * inv2 * gf[t] + bf[t];
  out[base + t + 256] = e1 * inv2 * gf[t + 256] + bf[t + 256];
}

// ---------------------------------------------------------------------------
extern "C" void kernel_launch(void* const* d_in, const int* in_sizes, int n_in,
                              void* d_out, int out_size, void* d_ws, size_t ws_size,
                              hipStream_t stream) {
  const float* src = (const float*)d_in[0];
  const float* q_w = (const float*)d_in[1];
  const float* k_w = (const float*)d_in[2];
  const float* v_w = (const float*)d_in[3];
  const float* r_w = (const float*)d_in[4];
  const float* o_w = (const float*)d_in[5];
  const float* rwb = (const float*)d_in[6];
  const float* rrb = (const float*)d_in[7];
  const float* w1  = (const float*)d_in[8];
  const float* b1  = (const float*)d_in[9];
  const float* w2  = (const float*)d_in[10];
  const float* b2  = (const float*)d_in[11];
  const float* g1  = (const float*)d_in[12];
  const float* be1 = (const float*)d_in[13];
  const float* g2  = (const float*)d_in[14];
  const float* be2 = (const float*)d_in[15];
  const float* gf  = (const float*)d_in[16];
  const float* bf  = (const float*)d_in[17];

  char* ws = (char*)d_ws;
  const size_t KB = 1024, MB = 1024 * 1024;
  ushort* srcb   = (ushort*)(ws);                        // 0    - 4 MB
  ushort* qkvw   = (ushort*)(ws + 4 * MB);               // 4    - 5.5
  ushort* rwT    = (ushort*)(ws + 5 * MB + 512 * KB);    // 5.5  - 6
  ushort* owb    = (ushort*)(ws + 6 * MB);               // 6    - 6.5
  ushort* w1b    = (ushort*)(ws + 6 * MB + 512 * KB);    // 6.5  - 8.5
  ushort* w2b    = (ushort*)(ws + 8 * MB + 512 * KB);    // 8.5  - 10.5
  ushort* peb    = (ushort*)(ws + 10 * MB + 512 * KB);   // 10.5 - 11.5
  ushort* qkv    = (ushort*)(ws + 11 * MB + 512 * KB);   // 11.5 - 23.5
  ushort* kprel  = (ushort*)(ws + 23 * MB + 512 * KB);   // 23.5 - 24.5
  ushort* qaF    = (ushort*)(ws + 24 * MB + 512 * KB);   // 24.5 - 28.5
  ushort* qbF    = (ushort*)(ws + 28 * MB + 512 * KB);   // 28.5 - 32.5
  ushort* kF     = (ushort*)(ws + 32 * MB + 512 * KB);   // 32.5 - 36.5
  ushort* vF     = (ushort*)(ws + 36 * MB + 512 * KB);   // 36.5 - 40.5
  ushort* kprelF = (ushort*)(ws + 40 * MB + 512 * KB);   // 40.5 - 41.6 (66 slots)
  ushort* av     = (ushort*)(ws + 42 * MB);              // 42   - 46
  float*  aoP    = (float*) (ws + 24 * MB + 512 * KB);   // 24.5 - 40.5 (2x8MB, over qaF..vF, dead after attn)
  float*  x1     = (float*) (ws + 46 * MB);              // 46   - 54
  ushort* x1b    = (ushort*)(ws + 42 * MB);              // 42   - 46 (over av, dead after o-proj)
  ushort* h      = (ushort*)(ws + 11 * MB + 512 * KB);   // 11.5 - 27.5 (qkv/kprel/aoP-head dead)
  float*  y2P    = (float*) (ws + 27 * MB + 512 * KB);   // 27.5 - 43.5 (2x8MB, aoP-tail/kprelF/x1b dead)
  float*  outp   = (float*)d_out;

  // fused preprocessing (pe + 4 cvt + weight transpose)
  prep_kernel<<<dim3(5248), 256, 0, stream>>>(src, o_w, w1, w2, q_w, k_w, v_w, r_w,
                                              peb, srcb, owb, w1b, w2b, qkvw, rwT);

  // fused QKV + kprel projections (one dispatch)
  gemm128_dual<<<dim3(416), 256, 0, stream>>>(srcb, qkvw, peb, rwT, qkv, kprel);

  // fused fragment-linear repack + kprelF
  repack_kernel<<<dim3(3600), 256, 0, stream>>>(qkv, rwb, rrb, kprel, qaF, qbF, kF, vF, kprelF);

  attn_mfma<<<dim3(32, 32), 256, 0, stream>>>(qaF, qbF, kF, kprelF, vF, av);

  // o-proj K-split x2 -> f32 partials; summed in ln_res
  gemm_split<<<dim3(4, 64, 2), 256, 0, stream>>>(av, owb, aoP, 4096, 512, 512, 256);
  ln_res_kernel<<<dim3(4096), 256, 0, stream>>>(aoP, aoP + 2097152, src, g1, be1, x1, x1b);

  gemm128_gelu<<<dim3(16, 32), 256, 0, stream>>>(x1b, w1b, b1, h, 4096, 2048, 512);
  // FFN2 K-split x2 -> f32 partials; summed (+b2) in ln_final
  gemm_split<<<dim3(4, 64, 2), 256, 0, stream>>>(h, w2b, y2P, 4096, 512, 2048, 1024);

  ln_final_kernel<<<dim3(4096), 256, 0, stream>>>(y2P, y2P + 2097152, b2, x1, g2, be2, gf, bf, outp);
}